// Round 1
// baseline (410.750 us; speedup 1.0000x reference)
//
#include <hip/hip_runtime.h>
#include <math.h>

// ---------------------------------------------------------------------------
// SpectralGroupAttention: conv1d+leaky+rmsnorm -> GEMM(inp|D) -> seqconv+silu
// -> GEMM(convlin) -> GEMM(fc1|fc2|fc3, softplus on delta) -> fused S6 scan
// -> GEMM(out_w, gated prologue) -> FNN head.
// All fp32. B=256, L=34, d=128, di=256, N=128, M=8704.
// ---------------------------------------------------------------------------

#define NB    256
#define LL    34
#define DD    128
#define DI    256
#define NN    128
#define MM    (NB*LL)       // 8704

__device__ __forceinline__ float silu_f(float x)  { return x / (1.f + __expf(-x)); }
__device__ __forceinline__ float softplus_f(float x) {
    return fmaxf(x, 0.f) + log1pf(__expf(-fabsf(x)));
}
__device__ __forceinline__ float leaky_f(float x) { return (x >= 0.f) ? x : 0.01f * x; }

// ---------------------------------------------------------------------------
// prep: concat weights/biases into workspace so fused GEMMs see one matrix.
// wcat1[512,128] = [inp_w ; D_w]; wcat3[512,256] = [fc1_w ; fc2_w ; fc3_w]
// bias1[512] = [inp_b | D_b];  bias3[512] = [fc1_b | fc2_b | fc3_b]
// ---------------------------------------------------------------------------
__global__ void prep_k(const float* __restrict__ inp_w, const float* __restrict__ D_w,
                       const float* __restrict__ fc1_w, const float* __restrict__ fc2_w,
                       const float* __restrict__ fc3_w,
                       const float* __restrict__ inp_b, const float* __restrict__ D_b,
                       const float* __restrict__ fc1_b, const float* __restrict__ fc2_b,
                       const float* __restrict__ fc3_b,
                       float* __restrict__ wcat1, float* __restrict__ wcat3,
                       float* __restrict__ bias1, float* __restrict__ bias3)
{
    int i = blockIdx.x * 256 + threadIdx.x;
    if (i < 65536)  wcat1[i] = (i < 32768) ? inp_w[i] : D_w[i - 32768];
    if (i < 131072) wcat3[i] = (i < 65536) ? fc1_w[i]
                              : (i < 98304 ? fc2_w[i - 65536] : fc3_w[i - 98304]);
    if (i < 512) {
        bias1[i] = (i < 256) ? inp_b[i] : D_b[i - 256];
        bias3[i] = (i < 256) ? fc1_b[i] : (i < 384 ? fc2_b[i - 256] : fc3_b[i - 384]);
    }
}

// ---------------------------------------------------------------------------
// conv1d(1->128, k=20, stride=5) + bias + leaky, then RMSNorm over d=128.
// One block per (b,l) row, 128 threads (= channels).
// ---------------------------------------------------------------------------
__global__ __launch_bounds__(128)
void conv_norm_k(const float* __restrict__ x, const float* __restrict__ cw,
                 const float* __restrict__ cb, const float* __restrict__ nw,
                 float* __restrict__ XN)
{
    int bl = blockIdx.x;             // b*34 + l
    int b = bl / LL, l = bl % LL;
    int c = threadIdx.x;
    const float* xr = x + (size_t)b * 189 + l * 5;   // wave-uniform base
    float g = cb[c];
    #pragma unroll
    for (int k = 0; k < 20; k++) g = fmaf(xr[k], cw[c * 20 + k], g);
    g = leaky_f(g);

    float s = g * g;
    #pragma unroll
    for (int m = 32; m >= 1; m >>= 1) s += __shfl_xor(s, m);
    __shared__ float wsum[2];
    if ((threadIdx.x & 63) == 0) wsum[threadIdx.x >> 6] = s;
    __syncthreads();
    float mean = (wsum[0] + wsum[1]) * (1.f / 128.f);
    float inv = 1.f / sqrtf(mean + 1e-5f);
    XN[(size_t)bl * DD + c] = g * inv * nw[c];
}

// ---------------------------------------------------------------------------
// Tiled fp32 GEMM: Y[r,c] = epi( sum_k A(r,k) * W[c,k] + bias[c] )
// BM=128, BN=64, 256 threads, micro 8x4, K-chunk 16.  M must be %128==0.
// PROLOG: 0 -> a = X[r,k];  1 -> a = silu(X[r,k]) * silu(X2[r,k])   (gate)
// EPI:    0 -> none;        1 -> softplus for cols < 256            (delta)
// ---------------------------------------------------------------------------
template <int K, int PROLOG, int EPI>
__global__ __launch_bounds__(256)
void gemm_k(const float* __restrict__ X, int ldx,
            const float* __restrict__ X2, int ldx2,
            const float* __restrict__ W, const float* __restrict__ bias,
            float* __restrict__ Y, int ldy)
{
    const int tid = threadIdx.x;
    const int r0 = blockIdx.x * 128;
    const int c0 = blockIdx.y * 64;
    __shared__ float As[16][132];
    __shared__ float Bs[16][68];

    const int tx = tid & 15;          // 0..15 -> 4 cols
    const int ty = tid >> 4;          // 0..15 -> 8 rows

    float acc[8][4];
    #pragma unroll
    for (int i = 0; i < 8; i++)
        #pragma unroll
        for (int j = 0; j < 4; j++) acc[i][j] = 0.f;

    const int a_r = tid >> 1, a_k = (tid & 1) * 8;       // A loader: 8 floats
    const int b_c = tid >> 2, b_k = (tid & 3) * 4;       // B loader: 4 floats

    for (int k0 = 0; k0 < K; k0 += 16) {
        // ---- stage A tile (transposed to As[k][r]) ----
        const float* xp = X + (size_t)(r0 + a_r) * ldx + k0 + a_k;
        float av[8];
        float4 v0 = *(const float4*)(xp);
        float4 v1 = *(const float4*)(xp + 4);
        av[0]=v0.x; av[1]=v0.y; av[2]=v0.z; av[3]=v0.w;
        av[4]=v1.x; av[5]=v1.y; av[6]=v1.z; av[7]=v1.w;
        if (PROLOG == 1) {
            const float* xq = X2 + (size_t)(r0 + a_r) * ldx2 + k0 + a_k;
            float4 w0 = *(const float4*)(xq);
            float4 w1 = *(const float4*)(xq + 4);
            float g2[8] = {w0.x,w0.y,w0.z,w0.w,w1.x,w1.y,w1.z,w1.w};
            #pragma unroll
            for (int j = 0; j < 8; j++) av[j] = silu_f(av[j]) * silu_f(g2[j]);
        }
        #pragma unroll
        for (int j = 0; j < 8; j++) As[a_k + j][a_r] = av[j];

        // ---- stage B tile (transposed to Bs[k][c]) ----
        float4 wv = *(const float4*)(W + (size_t)(c0 + b_c) * K + k0 + b_k);
        Bs[b_k + 0][b_c] = wv.x; Bs[b_k + 1][b_c] = wv.y;
        Bs[b_k + 2][b_c] = wv.z; Bs[b_k + 3][b_c] = wv.w;

        __syncthreads();
        #pragma unroll
        for (int kk = 0; kk < 16; kk++) {
            float4 a0 = *(const float4*)&As[kk][ty * 8];
            float4 a1 = *(const float4*)&As[kk][ty * 8 + 4];
            float4 b0 = *(const float4*)&Bs[kk][tx * 4];
            float avv[8] = {a0.x,a0.y,a0.z,a0.w,a1.x,a1.y,a1.z,a1.w};
            float bvv[4] = {b0.x,b0.y,b0.z,b0.w};
            #pragma unroll
            for (int i = 0; i < 8; i++)
                #pragma unroll
                for (int j = 0; j < 4; j++)
                    acc[i][j] = fmaf(avv[i], bvv[j], acc[i][j]);
        }
        __syncthreads();
    }

    const bool do_sp = (EPI == 1) && (c0 < 256);
    #pragma unroll
    for (int i = 0; i < 8; i++) {
        int r = r0 + ty * 8 + i;
        float4 o;
        o.x = acc[i][0] + bias[c0 + tx * 4 + 0];
        o.y = acc[i][1] + bias[c0 + tx * 4 + 1];
        o.z = acc[i][2] + bias[c0 + tx * 4 + 2];
        o.w = acc[i][3] + bias[c0 + tx * 4 + 3];
        if (do_sp) {
            o.x = softplus_f(o.x); o.y = softplus_f(o.y);
            o.z = softplus_f(o.z); o.w = softplus_f(o.w);
        }
        *(float4*)&Y[(size_t)r * ldy + c0 + tx * 4] = o;
    }
}

// ---------------------------------------------------------------------------
// seqconv: Conv1d over L as channels (34->34, k=3, pad=1 on the di axis)
// + bias + silu.  One block per b, 256 threads (= di columns).
// ---------------------------------------------------------------------------
__global__ __launch_bounds__(256)
void seqconv_k(const float* __restrict__ XP, int ldxp,
               const float* __restrict__ w, const float* __restrict__ bias,
               float* __restrict__ XC)
{
    int b = blockIdx.x;
    int j = threadIdx.x;
    __shared__ float xs_[LL][258];   // +1 zero pad each side
    for (int li = 0; li < LL; li++)
        xs_[li][j + 1] = XP[(size_t)(b * LL + li) * ldxp + j];
    if (j < LL) { xs_[j][0] = 0.f; xs_[j][257] = 0.f; }
    __syncthreads();

    float acc[LL];
    #pragma unroll
    for (int lo = 0; lo < LL; lo++) acc[lo] = bias[lo];

    for (int li = 0; li < LL; li++) {
        float xm  = xs_[li][j];
        float x0  = xs_[li][j + 1];
        float xp1 = xs_[li][j + 2];
        const float* wr = w + li * 3;      // w[lo][li][k] = w[lo*102 + li*3 + k]
        #pragma unroll
        for (int lo = 0; lo < LL; lo++) {
            acc[lo] = fmaf(xm,  wr[lo * 102 + 0], acc[lo]);
            acc[lo] = fmaf(x0,  wr[lo * 102 + 1], acc[lo]);
            acc[lo] = fmaf(xp1, wr[lo * 102 + 2], acc[lo]);
        }
    }
    #pragma unroll
    for (int lo = 0; lo < LL; lo++)
        XC[(size_t)(b * LL + lo) * DI + j] = silu_f(acc[lo]);
}

// ---------------------------------------------------------------------------
// Fused S6 scan.  Block = (b, 64 d's).  256 threads: sub = tid&15 owns
// n = sub*8..sub*8+7; pg = tid>>4 owns d = d0+pg*4..+3.  h[4][8] in regs.
// xs[b,l,d] = sum_n Cm[l,n] * h_l[d,n], h_l = exp(delta*A)*h_{l-1} + delta*x*Bm
// ---------------------------------------------------------------------------
__global__ __launch_bounds__(256)
void scan_k(const float* __restrict__ dBC,   // [8704,512] delta|Bm|Cm
            const float* __restrict__ Xc,    // [8704,256]
            const float* __restrict__ A,     // [256,128]
            float* __restrict__ XS)          // [8704,256]
{
    const int b  = blockIdx.y;
    const int d0 = blockIdx.x * 64;
    const int tid = threadIdx.x;
    __shared__ float sB[LL][128];
    __shared__ float sC[LL][128];
    __shared__ float sD[LL][64];
    __shared__ float sX[LL][64];

    for (int idx = tid; idx < LL * 128; idx += 256) {
        int l = idx >> 7, n = idx & 127;
        size_t row = (size_t)(b * LL + l) * 512;
        sB[l][n] = dBC[row + 256 + n];
        sC[l][n] = dBC[row + 384 + n];
    }
    for (int idx = tid; idx < LL * 64; idx += 256) {
        int l = idx >> 6, dd = idx & 63;
        sD[l][dd] = dBC[(size_t)(b * LL + l) * 512 + d0 + dd];
        sX[l][dd] = Xc [(size_t)(b * LL + l) * 256 + d0 + dd];
    }
    __syncthreads();

    const int sub = tid & 15;
    const int pg  = tid >> 4;
    const int n0  = sub * 8;
    const int dbase = d0 + pg * 4;

    float a[4][8], h[4][8];
    #pragma unroll
    for (int dd = 0; dd < 4; dd++) {
        float4 q0 = *(const float4*)&A[(size_t)(dbase + dd) * 128 + n0];
        float4 q1 = *(const float4*)&A[(size_t)(dbase + dd) * 128 + n0 + 4];
        a[dd][0]=q0.x; a[dd][1]=q0.y; a[dd][2]=q0.z; a[dd][3]=q0.w;
        a[dd][4]=q1.x; a[dd][5]=q1.y; a[dd][6]=q1.z; a[dd][7]=q1.w;
        #pragma unroll
        for (int j = 0; j < 8; j++) h[dd][j] = 0.f;
    }

    for (int l = 0; l < LL; l++) {
        float4 d4 = *(const float4*)&sD[l][pg * 4];
        float4 x4 = *(const float4*)&sX[l][pg * 4];
        float dl[4] = {d4.x, d4.y, d4.z, d4.w};
        float dx[4] = {d4.x * x4.x, d4.y * x4.y, d4.z * x4.z, d4.w * x4.w};

        float4 b0 = *(const float4*)&sB[l][n0];
        float4 b1 = *(const float4*)&sB[l][n0 + 4];
        float4 c0 = *(const float4*)&sC[l][n0];
        float4 c1 = *(const float4*)&sC[l][n0 + 4];
        float bv[8] = {b0.x,b0.y,b0.z,b0.w,b1.x,b1.y,b1.z,b1.w};
        float cv[8] = {c0.x,c0.y,c0.z,c0.w,c1.x,c1.y,c1.z,c1.w};

        float accd[4] = {0.f, 0.f, 0.f, 0.f};
        #pragma unroll
        for (int dd = 0; dd < 4; dd++) {
            #pragma unroll
            for (int j = 0; j < 8; j++) {
                float dA = __expf(dl[dd] * a[dd][j]);
                h[dd][j] = fmaf(dA, h[dd][j], dx[dd] * bv[j]);
                accd[dd] = fmaf(cv[j], h[dd][j], accd[dd]);
            }
        }
        #pragma unroll
        for (int dd = 0; dd < 4; dd++) {
            float v = accd[dd];
            v += __shfl_xor(v, 1);
            v += __shfl_xor(v, 2);
            v += __shfl_xor(v, 4);
            v += __shfl_xor(v, 8);
            accd[dd] = v;
        }
        if (sub == 0) {
            float4 o4 = make_float4(accd[0], accd[1], accd[2], accd[3]);
            *(float4*)&XS[(size_t)(b * LL + l) * 256 + dbase] = o4;
        }
    }
}

// ---------------------------------------------------------------------------
// FNN head: f[4352] -> leaky(f@W1.T+b1)[64] -> @W2.T+b2 -> out[32].
// One block per b. 64 outputs x 4 partial threads, then 32-thread tail.
// ---------------------------------------------------------------------------
__global__ __launch_bounds__(256)
void fnn_k(const float* __restrict__ F,
           const float* __restrict__ W1, const float* __restrict__ B1,
           const float* __restrict__ W2, const float* __restrict__ B2,
           float* __restrict__ out)
{
    int b = blockIdx.x;
    int tid = threadIdx.x;
    __shared__ float sf[LL * DD];   // 4352
    __shared__ float s1[64];
    for (int i = tid; i < LL * DD; i += 256) sf[i] = F[(size_t)b * LL * DD + i];
    __syncthreads();

    int o = tid >> 2, part = tid & 3;
    const float* w = W1 + (size_t)o * (LL * DD);
    float acc = 0.f;
    for (int k = part * 4; k < LL * DD; k += 16) {
        float4 wv = *(const float4*)(w + k);
        float4 fv = *(const float4*)(sf + k);
        acc += wv.x * fv.x + wv.y * fv.y + wv.z * fv.z + wv.w * fv.w;
    }
    acc += __shfl_xor(acc, 1);
    acc += __shfl_xor(acc, 2);
    if (part == 0) s1[o] = leaky_f(acc + B1[o]);
    __syncthreads();

    if (tid < 32) {
        float acc2 = B2[tid];
        const float* w2 = W2 + tid * 64;
        #pragma unroll
        for (int jj = 0; jj < 64; jj++) acc2 = fmaf(s1[jj], w2[jj], acc2);
        out[(size_t)b * 32 + tid] = acc2;
    }
}

// ---------------------------------------------------------------------------
extern "C" void kernel_launch(void* const* d_in, const int* in_sizes, int n_in,
                              void* d_out, int out_size, void* d_ws, size_t ws_size,
                              hipStream_t stream)
{
    const float* x        = (const float*)d_in[0];
    const float* conv_w   = (const float*)d_in[1];
    const float* conv_b   = (const float*)d_in[2];
    const float* norm_w   = (const float*)d_in[3];
    const float* inp_w    = (const float*)d_in[4];
    const float* inp_b    = (const float*)d_in[5];
    const float* seqconv_w= (const float*)d_in[6];
    const float* seqconv_b= (const float*)d_in[7];
    const float* convlin_w= (const float*)d_in[8];
    const float* convlin_b= (const float*)d_in[9];
    const float* fc1_w    = (const float*)d_in[10];
    const float* fc1_b    = (const float*)d_in[11];
    const float* fc2_w    = (const float*)d_in[12];
    const float* fc2_b    = (const float*)d_in[13];
    const float* fc3_w    = (const float*)d_in[14];
    const float* fc3_b    = (const float*)d_in[15];
    const float* A        = (const float*)d_in[16];
    const float* D_w      = (const float*)d_in[17];
    const float* D_b      = (const float*)d_in[18];
    const float* out_w    = (const float*)d_in[19];
    const float* out_b    = (const float*)d_in[20];
    const float* fnn1_w   = (const float*)d_in[21];
    const float* fnn1_b   = (const float*)d_in[22];
    const float* fnn2_w   = (const float*)d_in[23];
    const float* fnn2_b   = (const float*)d_in[24];

    float* ws    = (float*)d_ws;
    float* xn    = ws;                   // [8704,128]
    float* buf1  = ws + 1114112;         // [8704,512]  xp | dgate_pre
    float* xc    = ws + 5570560;         // [8704,256]  (reused as xs)
    float* xc2   = ws + 7798784;         // [8704,256]
    float* buf3  = ws + 10027008;        // [8704,512]  delta | Bm | Cm
    float* wcat1 = ws + 14483456;        // [512,128]
    float* wcat3 = ws + 14548992;        // [512,256]
    float* bias1 = ws + 14680064;        // [512]
    float* bias3 = ws + 14680576;        // [512]
    float* xs    = xc;                   // xc dead after convlin GEMM
    float* fout  = xn;                   // xn dead after first GEMM

    prep_k<<<512, 256, 0, stream>>>(inp_w, D_w, fc1_w, fc2_w, fc3_w,
                                    inp_b, D_b, fc1_b, fc2_b, fc3_b,
                                    wcat1, wcat3, bias1, bias3);

    conv_norm_k<<<MM, 128, 0, stream>>>(x, conv_w, conv_b, norm_w, xn);

    // xp | dgate_pre = xn @ [inp_w;D_w].T + [inp_b|D_b]
    gemm_k<128, 0, 0><<<dim3(MM / 128, 8), 256, 0, stream>>>(
        xn, 128, nullptr, 0, wcat1, bias1, buf1, 512);

    seqconv_k<<<NB, 256, 0, stream>>>(buf1, 512, seqconv_w, seqconv_b, xc);

    // xc2 = xc @ convlin_w.T + convlin_b
    gemm_k<256, 0, 0><<<dim3(MM / 128, 4), 256, 0, stream>>>(
        xc, 256, nullptr, 0, convlin_w, convlin_b, xc2, 256);

    // delta|Bm|Cm = xc2 @ [fc1;fc2;fc3].T + bias (softplus on delta cols)
    gemm_k<256, 0, 1><<<dim3(MM / 128, 8), 256, 0, stream>>>(
        xc2, 256, nullptr, 0, wcat3, bias3, buf3, 512);

    scan_k<<<dim3(4, NB), 256, 0, stream>>>(buf3, xc2, A, xs);

    // fout = (silu(xs)*silu(dgate_pre)) @ out_w.T + out_b
    gemm_k<256, 1, 0><<<dim3(MM / 128, 2), 256, 0, stream>>>(
        xs, 256, buf1 + 256, 512, out_w, out_b, fout, 128);

    fnn_k<<<NB, 256, 0, stream>>>(fout, fnn1_w, fnn1_b, fnn2_w, fnn2_b,
                                  (float*)d_out);
}

// Round 2
// 376.727 us; speedup vs baseline: 1.0903x; 1.0903x over previous
//
#include <hip/hip_runtime.h>
#include <math.h>

// ---------------------------------------------------------------------------
// SpectralGroupAttention: conv1d+leaky+rmsnorm -> GEMM(inp|D) -> seqconv+silu
// -> GEMM(convlin) -> GEMM(fc1|fc2|fc3, softplus on delta) -> fused S6 scan
// -> GEMM(out_w, gated prologue) -> split-K FNN head.
// All fp32. B=256, L=34, d=128, di=256, N=128, M=8704.
// ---------------------------------------------------------------------------

#define NB    256
#define LL    34
#define DD    128
#define DI    256
#define NN    128
#define MM    (NB*LL)       // 8704
#define LOG2E 1.4426950408889634f

__device__ __forceinline__ float silu_f(float x)  { return x / (1.f + __expf(-x)); }
__device__ __forceinline__ float softplus_f(float x) {
    return fmaxf(x, 0.f) + log1pf(__expf(-fabsf(x)));
}
__device__ __forceinline__ float leaky_f(float x) { return (x >= 0.f) ? x : 0.01f * x; }

// ---------------------------------------------------------------------------
// prep: concat weights/biases + transpose fnn1_w -> W1T[4352][64].
// grid 1088 x 256 covers 278528 items.
// ---------------------------------------------------------------------------
__global__ void prep_k(const float* __restrict__ inp_w, const float* __restrict__ D_w,
                       const float* __restrict__ fc1_w, const float* __restrict__ fc2_w,
                       const float* __restrict__ fc3_w,
                       const float* __restrict__ inp_b, const float* __restrict__ D_b,
                       const float* __restrict__ fc1_b, const float* __restrict__ fc2_b,
                       const float* __restrict__ fc3_b,
                       const float* __restrict__ W1,
                       float* __restrict__ wcat1, float* __restrict__ wcat3,
                       float* __restrict__ bias1, float* __restrict__ bias3,
                       float* __restrict__ W1T)
{
    int i = blockIdx.x * 256 + threadIdx.x;
    if (i < 65536)  wcat1[i] = (i < 32768) ? inp_w[i] : D_w[i - 32768];
    if (i < 131072) wcat3[i] = (i < 65536) ? fc1_w[i]
                              : (i < 98304 ? fc2_w[i - 65536] : fc3_w[i - 98304]);
    if (i < 278528) W1T[i] = W1[(size_t)(i & 63) * 4352 + (i >> 6)];
    if (i < 512) {
        bias1[i] = (i < 256) ? inp_b[i] : D_b[i - 256];
        bias3[i] = (i < 256) ? fc1_b[i] : (i < 384 ? fc2_b[i - 256] : fc3_b[i - 384]);
    }
}

// ---------------------------------------------------------------------------
// conv1d(1->128, k=20, stride=5) + bias + leaky, then RMSNorm over d=128.
// One block per (b,l) row, 128 threads (= channels).
// ---------------------------------------------------------------------------
__global__ __launch_bounds__(128)
void conv_norm_k(const float* __restrict__ x, const float* __restrict__ cw,
                 const float* __restrict__ cb, const float* __restrict__ nw,
                 float* __restrict__ XN)
{
    int bl = blockIdx.x;             // b*34 + l
    int b = bl / LL, l = bl % LL;
    int c = threadIdx.x;
    const float* xr = x + (size_t)b * 189 + l * 5;   // wave-uniform base
    float g = cb[c];
    #pragma unroll
    for (int k = 0; k < 20; k++) g = fmaf(xr[k], cw[c * 20 + k], g);
    g = leaky_f(g);

    float s = g * g;
    #pragma unroll
    for (int m = 32; m >= 1; m >>= 1) s += __shfl_xor(s, m);
    __shared__ float wsum[2];
    if ((threadIdx.x & 63) == 0) wsum[threadIdx.x >> 6] = s;
    __syncthreads();
    float mean = (wsum[0] + wsum[1]) * (1.f / 128.f);
    float inv = 1.f / sqrtf(mean + 1e-5f);
    XN[(size_t)bl * DD + c] = g * inv * nw[c];
}

// ---------------------------------------------------------------------------
// Tiled fp32 GEMM: Y[r,c] = epi( sum_k A(r,k) * W[c,k] + bias[c] )
// BM=128, BN=64, 256 threads, micro 8x4, K-chunk 16.  M must be %128==0.
// PROLOG: 0 -> a = X[r,k];  1 -> a = silu(X[r,k]) * silu(X2[r,k])   (gate)
// EPI:    0 -> none;        1 -> softplus for cols < 256            (delta)
// ---------------------------------------------------------------------------
template <int K, int PROLOG, int EPI>
__global__ __launch_bounds__(256)
void gemm_k(const float* __restrict__ X, int ldx,
            const float* __restrict__ X2, int ldx2,
            const float* __restrict__ W, const float* __restrict__ bias,
            float* __restrict__ Y, int ldy)
{
    const int tid = threadIdx.x;
    const int r0 = blockIdx.x * 128;
    const int c0 = blockIdx.y * 64;
    __shared__ float As[16][132];
    __shared__ float Bs[16][68];

    const int tx = tid & 15;          // 0..15 -> 4 cols
    const int ty = tid >> 4;          // 0..15 -> 8 rows

    float acc[8][4];
    #pragma unroll
    for (int i = 0; i < 8; i++)
        #pragma unroll
        for (int j = 0; j < 4; j++) acc[i][j] = 0.f;

    const int a_r = tid >> 1, a_k = (tid & 1) * 8;       // A loader: 8 floats
    const int b_c = tid >> 2, b_k = (tid & 3) * 4;       // B loader: 4 floats

    for (int k0 = 0; k0 < K; k0 += 16) {
        // ---- stage A tile (transposed to As[k][r]) ----
        const float* xp = X + (size_t)(r0 + a_r) * ldx + k0 + a_k;
        float av[8];
        float4 v0 = *(const float4*)(xp);
        float4 v1 = *(const float4*)(xp + 4);
        av[0]=v0.x; av[1]=v0.y; av[2]=v0.z; av[3]=v0.w;
        av[4]=v1.x; av[5]=v1.y; av[6]=v1.z; av[7]=v1.w;
        if (PROLOG == 1) {
            const float* xq = X2 + (size_t)(r0 + a_r) * ldx2 + k0 + a_k;
            float4 w0 = *(const float4*)(xq);
            float4 w1 = *(const float4*)(xq + 4);
            float g2[8] = {w0.x,w0.y,w0.z,w0.w,w1.x,w1.y,w1.z,w1.w};
            #pragma unroll
            for (int j = 0; j < 8; j++) av[j] = silu_f(av[j]) * silu_f(g2[j]);
        }
        #pragma unroll
        for (int j = 0; j < 8; j++) As[a_k + j][a_r] = av[j];

        // ---- stage B tile (transposed to Bs[k][c]) ----
        float4 wv = *(const float4*)(W + (size_t)(c0 + b_c) * K + k0 + b_k);
        Bs[b_k + 0][b_c] = wv.x; Bs[b_k + 1][b_c] = wv.y;
        Bs[b_k + 2][b_c] = wv.z; Bs[b_k + 3][b_c] = wv.w;

        __syncthreads();
        #pragma unroll
        for (int kk = 0; kk < 16; kk++) {
            float4 a0 = *(const float4*)&As[kk][ty * 8];
            float4 a1 = *(const float4*)&As[kk][ty * 8 + 4];
            float4 b0 = *(const float4*)&Bs[kk][tx * 4];
            float avv[8] = {a0.x,a0.y,a0.z,a0.w,a1.x,a1.y,a1.z,a1.w};
            float bvv[4] = {b0.x,b0.y,b0.z,b0.w};
            #pragma unroll
            for (int i = 0; i < 8; i++)
                #pragma unroll
                for (int j = 0; j < 4; j++)
                    acc[i][j] = fmaf(avv[i], bvv[j], acc[i][j]);
        }
        __syncthreads();
    }

    const bool do_sp = (EPI == 1) && (c0 < 256);
    #pragma unroll
    for (int i = 0; i < 8; i++) {
        int r = r0 + ty * 8 + i;
        float4 o;
        o.x = acc[i][0] + bias[c0 + tx * 4 + 0];
        o.y = acc[i][1] + bias[c0 + tx * 4 + 1];
        o.z = acc[i][2] + bias[c0 + tx * 4 + 2];
        o.w = acc[i][3] + bias[c0 + tx * 4 + 3];
        if (do_sp) {
            o.x = softplus_f(o.x); o.y = softplus_f(o.y);
            o.z = softplus_f(o.z); o.w = softplus_f(o.w);
        }
        *(float4*)&Y[(size_t)r * ldy + c0 + tx * 4] = o;
    }
}

// ---------------------------------------------------------------------------
// seqconv: Conv1d over L as channels (34->34, k=3, pad=1 on the di axis)
// + bias + silu.  One block per b, 256 threads (= di columns).
// ---------------------------------------------------------------------------
__global__ __launch_bounds__(256)
void seqconv_k(const float* __restrict__ XP, int ldxp,
               const float* __restrict__ w, const float* __restrict__ bias,
               float* __restrict__ XC)
{
    int b = blockIdx.x;
    int j = threadIdx.x;
    __shared__ float xs_[LL][258];   // +1 zero pad each side
    for (int li = 0; li < LL; li++)
        xs_[li][j + 1] = XP[(size_t)(b * LL + li) * ldxp + j];
    if (j < LL) { xs_[j][0] = 0.f; xs_[j][257] = 0.f; }
    __syncthreads();

    float acc[LL];
    #pragma unroll
    for (int lo = 0; lo < LL; lo++) acc[lo] = bias[lo];

    for (int li = 0; li < LL; li++) {
        float xm  = xs_[li][j];
        float x0  = xs_[li][j + 1];
        float xp1 = xs_[li][j + 2];
        const float* wr = w + li * 3;      // w[lo][li][k] = w[lo*102 + li*3 + k]
        #pragma unroll
        for (int lo = 0; lo < LL; lo++) {
            acc[lo] = fmaf(xm,  wr[lo * 102 + 0], acc[lo]);
            acc[lo] = fmaf(x0,  wr[lo * 102 + 1], acc[lo]);
            acc[lo] = fmaf(xp1, wr[lo * 102 + 2], acc[lo]);
        }
    }
    #pragma unroll
    for (int lo = 0; lo < LL; lo++)
        XC[(size_t)(b * LL + lo) * DI + j] = silu_f(acc[lo]);
}

// ---------------------------------------------------------------------------
// Fused S6 scan, LDS-free.  Block = (b, 64 d's).  256 threads:
// sub = tid&15 owns n in {sub*4..+3} u {64+sub*4..+3};  pg = tid>>4 owns
// d = d0+pg*4..+3.  h[4][8] in regs; next-l fragments register-prefetched.
// ---------------------------------------------------------------------------
__global__ __launch_bounds__(256)
void scan_k(const float* __restrict__ dBC,   // [8704,512] delta|Bm|Cm
            const float* __restrict__ Xc,    // [8704,256]
            const float* __restrict__ A,     // [256,128]
            float* __restrict__ XS)          // [8704,256]
{
    const int b  = blockIdx.y;
    const int d0 = blockIdx.x * 64;
    const int tid = threadIdx.x;
    const int sub = tid & 15;
    const int pg  = tid >> 4;
    const int dbase = d0 + pg * 4;
    const int nA = sub * 4;

    const float* rowD = dBC + (size_t)b * LL * 512;
    const float* rowX = Xc  + (size_t)b * LL * 256;

    float a[4][8], h[4][8];
    #pragma unroll
    for (int dd = 0; dd < 4; dd++) {
        const float* Ar = A + (size_t)(dbase + dd) * NN;
        float4 q0 = *(const float4*)(Ar + nA);
        float4 q1 = *(const float4*)(Ar + 64 + nA);
        a[dd][0]=q0.x; a[dd][1]=q0.y; a[dd][2]=q0.z; a[dd][3]=q0.w;
        a[dd][4]=q1.x; a[dd][5]=q1.y; a[dd][6]=q1.z; a[dd][7]=q1.w;
        #pragma unroll
        for (int j = 0; j < 8; j++) h[dd][j] = 0.f;
    }

    // prefetch l = 0 fragments
    float4 pD  = *(const float4*)(rowD + dbase);
    float4 pX  = *(const float4*)(rowX + dbase);
    float4 pB0 = *(const float4*)(rowD + 256 + nA);
    float4 pB1 = *(const float4*)(rowD + 256 + 64 + nA);
    float4 pC0 = *(const float4*)(rowD + 384 + nA);
    float4 pC1 = *(const float4*)(rowD + 384 + 64 + nA);

    for (int l = 0; l < LL; l++) {
        float4 cD = pD, cX = pX, cB0 = pB0, cB1 = pB1, cC0 = pC0, cC1 = pC1;
        if (l + 1 < LL) {
            const float* nD = rowD + (l + 1) * 512;
            const float* nX = rowX + (l + 1) * 256;
            pD  = *(const float4*)(nD + dbase);
            pX  = *(const float4*)(nX + dbase);
            pB0 = *(const float4*)(nD + 256 + nA);
            pB1 = *(const float4*)(nD + 256 + 64 + nA);
            pC0 = *(const float4*)(nD + 384 + nA);
            pC1 = *(const float4*)(nD + 384 + 64 + nA);
        }

        float dl[4] = {cD.x * LOG2E, cD.y * LOG2E, cD.z * LOG2E, cD.w * LOG2E};
        float dx[4] = {cD.x * cX.x, cD.y * cX.y, cD.z * cX.z, cD.w * cX.w};
        float bv[8] = {cB0.x,cB0.y,cB0.z,cB0.w,cB1.x,cB1.y,cB1.z,cB1.w};
        float cv[8] = {cC0.x,cC0.y,cC0.z,cC0.w,cC1.x,cC1.y,cC1.z,cC1.w};

        float accd[4] = {0.f, 0.f, 0.f, 0.f};
        #pragma unroll
        for (int dd = 0; dd < 4; dd++) {
            #pragma unroll
            for (int j = 0; j < 8; j++) {
                float dA = exp2f(dl[dd] * a[dd][j]);
                h[dd][j] = fmaf(dA, h[dd][j], dx[dd] * bv[j]);
                accd[dd] = fmaf(cv[j], h[dd][j], accd[dd]);
            }
        }
        #pragma unroll
        for (int dd = 0; dd < 4; dd++) {
            float v = accd[dd];
            v += __shfl_xor(v, 1);
            v += __shfl_xor(v, 2);
            v += __shfl_xor(v, 4);
            v += __shfl_xor(v, 8);
            accd[dd] = v;
        }
        if (sub == 0) {
            float4 o4 = make_float4(accd[0], accd[1], accd[2], accd[3]);
            *(float4*)&XS[(size_t)(b * LL + l) * 256 + dbase] = o4;
        }
    }
}

// ---------------------------------------------------------------------------
// FNN stage 1: partials[kc][b][o] = F[b, kc*256..+255] @ W1T[kc*256..+255, o]
// grid (16 btiles, 17 kchunks), 256 threads: o = tid&63, bq = tid>>6 (4 b's).
// Deterministic (no atomics): each block owns its [kc][16 b] slice.
// ---------------------------------------------------------------------------
__global__ __launch_bounds__(256)
void fnn1_k(const float* __restrict__ F, const float* __restrict__ W1T,
            float* __restrict__ partials)
{
    const int btile = blockIdx.x;
    const int kc    = blockIdx.y;
    const int tid   = threadIdx.x;
    __shared__ float sf[16][260];
    for (int i = tid; i < 16 * 256; i += 256) {
        int r = i >> 8, c = i & 255;
        sf[r][c] = F[(size_t)(btile * 16 + r) * 4352 + kc * 256 + c];
    }
    __syncthreads();

    const int o  = tid & 63;
    const int bq = tid >> 6;
    const float* w = W1T + (size_t)(kc * 256) * 64 + o;
    float acc[4] = {0.f, 0.f, 0.f, 0.f};
    for (int k = 0; k < 256; k += 4) {
        float w0 = w[(size_t)(k + 0) * 64];
        float w1 = w[(size_t)(k + 1) * 64];
        float w2 = w[(size_t)(k + 2) * 64];
        float w3 = w[(size_t)(k + 3) * 64];
        #pragma unroll
        for (int bj = 0; bj < 4; bj++) {
            float4 f4 = *(const float4*)&sf[bq * 4 + bj][k];
            acc[bj] = fmaf(w0, f4.x, acc[bj]);
            acc[bj] = fmaf(w1, f4.y, acc[bj]);
            acc[bj] = fmaf(w2, f4.z, acc[bj]);
            acc[bj] = fmaf(w3, f4.w, acc[bj]);
        }
    }
    #pragma unroll
    for (int bj = 0; bj < 4; bj++)
        partials[(size_t)kc * 16384 + (btile * 16 + bq * 4 + bj) * 64 + o] = acc[bj];
}

// ---------------------------------------------------------------------------
// FNN stage 2: reduce 17 partials, leaky, then @fnn2_w.T + b2 -> out[b][32].
// One block per b, 64 threads.
// ---------------------------------------------------------------------------
__global__ __launch_bounds__(64)
void fnn2_k(const float* __restrict__ partials,
            const float* __restrict__ B1,
            const float* __restrict__ W2, const float* __restrict__ B2,
            float* __restrict__ out)
{
    int b = blockIdx.x;
    int t = threadIdx.x;
    __shared__ float s1[64];
    float acc = B1[t];
    #pragma unroll
    for (int kc = 0; kc < 17; kc++)
        acc += partials[(size_t)kc * 16384 + b * 64 + t];
    s1[t] = leaky_f(acc);
    __syncthreads();

    if (t < 32) {
        float acc2 = B2[t];
        const float* w2 = W2 + t * 64;
        #pragma unroll
        for (int j = 0; j < 64; j++) acc2 = fmaf(s1[j], w2[j], acc2);
        out[(size_t)b * 32 + t] = acc2;
    }
}

// ---------------------------------------------------------------------------
extern "C" void kernel_launch(void* const* d_in, const int* in_sizes, int n_in,
                              void* d_out, int out_size, void* d_ws, size_t ws_size,
                              hipStream_t stream)
{
    const float* x        = (const float*)d_in[0];
    const float* conv_w   = (const float*)d_in[1];
    const float* conv_b   = (const float*)d_in[2];
    const float* norm_w   = (const float*)d_in[3];
    const float* inp_w    = (const float*)d_in[4];
    const float* inp_b    = (const float*)d_in[5];
    const float* seqconv_w= (const float*)d_in[6];
    const float* seqconv_b= (const float*)d_in[7];
    const float* convlin_w= (const float*)d_in[8];
    const float* convlin_b= (const float*)d_in[9];
    const float* fc1_w    = (const float*)d_in[10];
    const float* fc1_b    = (const float*)d_in[11];
    const float* fc2_w    = (const float*)d_in[12];
    const float* fc2_b    = (const float*)d_in[13];
    const float* fc3_w    = (const float*)d_in[14];
    const float* fc3_b    = (const float*)d_in[15];
    const float* A        = (const float*)d_in[16];
    const float* D_w      = (const float*)d_in[17];
    const float* D_b      = (const float*)d_in[18];
    const float* out_w    = (const float*)d_in[19];
    const float* out_b    = (const float*)d_in[20];
    const float* fnn1_w   = (const float*)d_in[21];
    const float* fnn1_b   = (const float*)d_in[22];
    const float* fnn2_w   = (const float*)d_in[23];
    const float* fnn2_b   = (const float*)d_in[24];

    float* ws    = (float*)d_ws;
    float* xn    = ws;                   // [8704,128]
    float* buf1  = ws + 1114112;         // [8704,512]  xp | dgate_pre
    float* xc    = ws + 5570560;         // [8704,256]  (reused as xs)
    float* xc2   = ws + 7798784;         // [8704,256]
    float* buf3  = ws + 10027008;        // [8704,512]  delta|Bm|Cm, later partials
    float* wcat1 = ws + 14483456;        // [512,128]
    float* wcat3 = ws + 14548992;        // [512,256]
    float* bias1 = ws + 14680064;        // [512]
    float* bias3 = ws + 14680576;        // [512]
    float* w1t   = ws + 14681088;        // [4352,64]
    float* xs    = xc;                   // xc dead after convlin GEMM
    float* fout  = xn;                   // xn dead after first GEMM
    float* partials = buf3;              // buf3 dead after scan_k

    prep_k<<<1088, 256, 0, stream>>>(inp_w, D_w, fc1_w, fc2_w, fc3_w,
                                     inp_b, D_b, fc1_b, fc2_b, fc3_b,
                                     fnn1_w, wcat1, wcat3, bias1, bias3, w1t);

    conv_norm_k<<<MM, 128, 0, stream>>>(x, conv_w, conv_b, norm_w, xn);

    // xp | dgate_pre = xn @ [inp_w;D_w].T + [inp_b|D_b]
    gemm_k<128, 0, 0><<<dim3(MM / 128, 8), 256, 0, stream>>>(
        xn, 128, nullptr, 0, wcat1, bias1, buf1, 512);

    seqconv_k<<<NB, 256, 0, stream>>>(buf1, 512, seqconv_w, seqconv_b, xc);

    // xc2 = xc @ convlin_w.T + convlin_b
    gemm_k<256, 0, 0><<<dim3(MM / 128, 4), 256, 0, stream>>>(
        xc, 256, nullptr, 0, convlin_w, convlin_b, xc2, 256);

    // delta|Bm|Cm = xc2 @ [fc1;fc2;fc3].T + bias (softplus on delta cols)
    gemm_k<256, 0, 1><<<dim3(MM / 128, 8), 256, 0, stream>>>(
        xc2, 256, nullptr, 0, wcat3, bias3, buf3, 512);

    scan_k<<<dim3(4, NB), 256, 0, stream>>>(buf3, xc2, A, xs);

    // fout = (silu(xs)*silu(dgate_pre)) @ out_w.T + out_b
    gemm_k<256, 1, 0><<<dim3(MM / 128, 2), 256, 0, stream>>>(
        xs, 256, buf1 + 256, 512, out_w, out_b, fout, 128);

    fnn1_k<<<dim3(16, 17), 256, 0, stream>>>(fout, w1t, partials);
    fnn2_k<<<NB, 64, 0, stream>>>(partials, fnn1_b, fnn2_w, fnn2_b,
                                  (float*)d_out);
}

// Round 3
// 329.028 us; speedup vs baseline: 1.2484x; 1.1450x over previous
//
#include <hip/hip_runtime.h>
#include <math.h>

// ---------------------------------------------------------------------------
// SpectralGroupAttention: conv1d+leaky+rmsnorm -> GEMM(inp|D) -> seqconv+silu
// -> GEMM(convlin) -> GEMM(fc1|fc2|fc3, softplus on delta) -> fused S6 scan
// -> GEMM(out_w, gated prologue) -> split-K FNN head.
// All fp32. B=256, L=34, d=128, di=256, N=128, M=8704.
// ---------------------------------------------------------------------------

#define NB    256
#define LL    34
#define DD    128
#define DI    256
#define NN    128
#define MM    (NB*LL)       // 8704

__device__ __forceinline__ float silu_f(float x)  { return x / (1.f + __expf(-x)); }
// fast softplus: __logf/__expf are native v_log/v_exp (2 instrs each); the
// precise log1pf/exp2f OCML paths are ~8 instrs and showed up as VALU bloat.
__device__ __forceinline__ float softplus_f(float x) {
    return fmaxf(x, 0.f) + __logf(1.f + __expf(-fabsf(x)));
}
__device__ __forceinline__ float leaky_f(float x) { return (x >= 0.f) ? x : 0.01f * x; }

// ---------------------------------------------------------------------------
// prep: concat weights/biases + transpose fnn1_w -> W1T[4352][64].
// grid 1088 x 256 covers 278528 items.
// ---------------------------------------------------------------------------
__global__ void prep_k(const float* __restrict__ inp_w, const float* __restrict__ D_w,
                       const float* __restrict__ fc1_w, const float* __restrict__ fc2_w,
                       const float* __restrict__ fc3_w,
                       const float* __restrict__ inp_b, const float* __restrict__ D_b,
                       const float* __restrict__ fc1_b, const float* __restrict__ fc2_b,
                       const float* __restrict__ fc3_b,
                       const float* __restrict__ W1,
                       float* __restrict__ wcat1, float* __restrict__ wcat3,
                       float* __restrict__ bias1, float* __restrict__ bias3,
                       float* __restrict__ W1T)
{
    int i = blockIdx.x * 256 + threadIdx.x;
    if (i < 65536)  wcat1[i] = (i < 32768) ? inp_w[i] : D_w[i - 32768];
    if (i < 131072) wcat3[i] = (i < 65536) ? fc1_w[i]
                              : (i < 98304 ? fc2_w[i - 65536] : fc3_w[i - 98304]);
    if (i < 278528) W1T[i] = W1[(size_t)(i & 63) * 4352 + (i >> 6)];
    if (i < 512) {
        bias1[i] = (i < 256) ? inp_b[i] : D_b[i - 256];
        bias3[i] = (i < 256) ? fc1_b[i] : (i < 384 ? fc2_b[i - 256] : fc3_b[i - 384]);
    }
}

// ---------------------------------------------------------------------------
// conv1d(1->128, k=20, stride=5) + bias + leaky, then RMSNorm over d=128.
// One block per (b,l) row, 128 threads (= channels).
// ---------------------------------------------------------------------------
__global__ __launch_bounds__(128)
void conv_norm_k(const float* __restrict__ x, const float* __restrict__ cw,
                 const float* __restrict__ cb, const float* __restrict__ nw,
                 float* __restrict__ XN)
{
    int bl = blockIdx.x;             // b*34 + l
    int b = bl / LL, l = bl % LL;
    int c = threadIdx.x;
    const float* xr = x + (size_t)b * 189 + l * 5;   // wave-uniform base
    float g = cb[c];
    #pragma unroll
    for (int k = 0; k < 20; k++) g = fmaf(xr[k], cw[c * 20 + k], g);
    g = leaky_f(g);

    float s = g * g;
    #pragma unroll
    for (int m = 32; m >= 1; m >>= 1) s += __shfl_xor(s, m);
    __shared__ float wsum[2];
    if ((threadIdx.x & 63) == 0) wsum[threadIdx.x >> 6] = s;
    __syncthreads();
    float mean = (wsum[0] + wsum[1]) * (1.f / 128.f);
    float inv = 1.f / sqrtf(mean + 1e-5f);
    XN[(size_t)bl * DD + c] = g * inv * nw[c];
}

// ---------------------------------------------------------------------------
// Tiled fp32 GEMM: Y[r,c] = epi( sum_k A(r,k) * W[c,k] + bias[c] )
// BM=128, BN=64, 256 threads, micro 8x4, K-chunk 16.  M must be %128==0.
// PROLOG: 0 -> a = X[r,k];  1 -> a = silu(X[r,k]) * silu(X2[r,k])   (gate)
// EPI:    0 -> none;        1 -> softplus for cols < 256            (delta)
// ---------------------------------------------------------------------------
template <int K, int PROLOG, int EPI>
__global__ __launch_bounds__(256)
void gemm_k(const float* __restrict__ X, int ldx,
            const float* __restrict__ X2, int ldx2,
            const float* __restrict__ W, const float* __restrict__ bias,
            float* __restrict__ Y, int ldy)
{
    const int tid = threadIdx.x;
    const int r0 = blockIdx.x * 128;
    const int c0 = blockIdx.y * 64;
    __shared__ float As[16][132];
    __shared__ float Bs[16][68];

    const int tx = tid & 15;          // 0..15 -> 4 cols
    const int ty = tid >> 4;          // 0..15 -> 8 rows

    float acc[8][4];
    #pragma unroll
    for (int i = 0; i < 8; i++)
        #pragma unroll
        for (int j = 0; j < 4; j++) acc[i][j] = 0.f;

    const int a_r = tid >> 1, a_k = (tid & 1) * 8;       // A loader: 8 floats
    const int b_c = tid >> 2, b_k = (tid & 3) * 4;       // B loader: 4 floats

    for (int k0 = 0; k0 < K; k0 += 16) {
        // ---- stage A tile (transposed to As[k][r]) ----
        const float* xp = X + (size_t)(r0 + a_r) * ldx + k0 + a_k;
        float av[8];
        float4 v0 = *(const float4*)(xp);
        float4 v1 = *(const float4*)(xp + 4);
        av[0]=v0.x; av[1]=v0.y; av[2]=v0.z; av[3]=v0.w;
        av[4]=v1.x; av[5]=v1.y; av[6]=v1.z; av[7]=v1.w;
        if (PROLOG == 1) {
            const float* xq = X2 + (size_t)(r0 + a_r) * ldx2 + k0 + a_k;
            float4 w0 = *(const float4*)(xq);
            float4 w1 = *(const float4*)(xq + 4);
            float g2[8] = {w0.x,w0.y,w0.z,w0.w,w1.x,w1.y,w1.z,w1.w};
            #pragma unroll
            for (int j = 0; j < 8; j++) av[j] = silu_f(av[j]) * silu_f(g2[j]);
        }
        #pragma unroll
        for (int j = 0; j < 8; j++) As[a_k + j][a_r] = av[j];

        // ---- stage B tile (transposed to Bs[k][c]) ----
        float4 wv = *(const float4*)(W + (size_t)(c0 + b_c) * K + k0 + b_k);
        Bs[b_k + 0][b_c] = wv.x; Bs[b_k + 1][b_c] = wv.y;
        Bs[b_k + 2][b_c] = wv.z; Bs[b_k + 3][b_c] = wv.w;

        __syncthreads();
        #pragma unroll
        for (int kk = 0; kk < 16; kk++) {
            float4 a0 = *(const float4*)&As[kk][ty * 8];
            float4 a1 = *(const float4*)&As[kk][ty * 8 + 4];
            float4 b0 = *(const float4*)&Bs[kk][tx * 4];
            float avv[8] = {a0.x,a0.y,a0.z,a0.w,a1.x,a1.y,a1.z,a1.w};
            float bvv[4] = {b0.x,b0.y,b0.z,b0.w};
            #pragma unroll
            for (int i = 0; i < 8; i++)
                #pragma unroll
                for (int j = 0; j < 4; j++)
                    acc[i][j] = fmaf(avv[i], bvv[j], acc[i][j]);
        }
        __syncthreads();
    }

    const bool do_sp = (EPI == 1) && (c0 < 256);
    #pragma unroll
    for (int i = 0; i < 8; i++) {
        int r = r0 + ty * 8 + i;
        float4 o;
        o.x = acc[i][0] + bias[c0 + tx * 4 + 0];
        o.y = acc[i][1] + bias[c0 + tx * 4 + 1];
        o.z = acc[i][2] + bias[c0 + tx * 4 + 2];
        o.w = acc[i][3] + bias[c0 + tx * 4 + 3];
        if (do_sp) {
            o.x = softplus_f(o.x); o.y = softplus_f(o.y);
            o.z = softplus_f(o.z); o.w = softplus_f(o.w);
        }
        *(float4*)&Y[(size_t)r * ldy + c0 + tx * 4] = o;
    }
}

// ---------------------------------------------------------------------------
// seqconv: Conv1d over L as channels (34->34, k=3, pad=1 on the di axis)
// + bias + silu.  One block per b, 256 threads (= di columns).
// ---------------------------------------------------------------------------
__global__ __launch_bounds__(256)
void seqconv_k(const float* __restrict__ XP, int ldxp,
               const float* __restrict__ w, const float* __restrict__ bias,
               float* __restrict__ XC)
{
    int b = blockIdx.x;
    int j = threadIdx.x;
    __shared__ float xs_[LL][258];   // +1 zero pad each side
    for (int li = 0; li < LL; li++)
        xs_[li][j + 1] = XP[(size_t)(b * LL + li) * ldxp + j];
    if (j < LL) { xs_[j][0] = 0.f; xs_[j][257] = 0.f; }
    __syncthreads();

    float acc[LL];
    #pragma unroll
    for (int lo = 0; lo < LL; lo++) acc[lo] = bias[lo];

    for (int li = 0; li < LL; li++) {
        float xm  = xs_[li][j];
        float x0  = xs_[li][j + 1];
        float xp1 = xs_[li][j + 2];
        const float* wr = w + li * 3;      // w[lo][li][k] = w[lo*102 + li*3 + k]
        #pragma unroll
        for (int lo = 0; lo < LL; lo++) {
            acc[lo] = fmaf(xm,  wr[lo * 102 + 0], acc[lo]);
            acc[lo] = fmaf(x0,  wr[lo * 102 + 1], acc[lo]);
            acc[lo] = fmaf(xp1, wr[lo * 102 + 2], acc[lo]);
        }
    }
    #pragma unroll
    for (int lo = 0; lo < LL; lo++)
        XC[(size_t)(b * LL + lo) * DI + j] = silu_f(acc[lo]);
}

// ---------------------------------------------------------------------------
// Fused S6 scan, LDS-free.  Block = (b, 64 d's).  256 threads:
// sub = tid&15 owns n in {sub*4..+3} u {64+sub*4..+3};  pg = tid>>4 owns
// d = d0+pg*4..+3.  h[4][8] in regs; next-l fragments register-prefetched
// through 3 walking pointers (constant strides, immediate quad offsets).
// UNI fast path: when A[d,n] is constant along n for this thread's rows
// (true for the given A = ones/sqrt(N)), one exp per (l,d) instead of 8.
// ---------------------------------------------------------------------------
template <bool UNI>
__device__ __forceinline__ void scan_loop(
    const float* __restrict__ pD,    // walks b*LL*512 + dbase, stride 512
    const float* __restrict__ pBC,   // walks b*LL*512 + 256 + nA, stride 512
    const float* __restrict__ pX,    // walks b*LL*256 + dbase, stride 256
    float* __restrict__ pO,          // walks b*LL*256 + dbase, stride 256
    float a[4][8], float h[4][8], int sub)
{
    float4 fD  = *(const float4*)(pD);
    float4 fX  = *(const float4*)(pX);
    float4 fB0 = *(const float4*)(pBC);
    float4 fB1 = *(const float4*)(pBC + 64);
    float4 fC0 = *(const float4*)(pBC + 128);
    float4 fC1 = *(const float4*)(pBC + 192);

    for (int l = 0; l < LL; l++) {
        float4 cD = fD, cX = fX, cB0 = fB0, cB1 = fB1, cC0 = fC0, cC1 = fC1;
        pD += 512; pBC += 512; pX += 256;
        if (l + 1 < LL) {
            fD  = *(const float4*)(pD);
            fX  = *(const float4*)(pX);
            fB0 = *(const float4*)(pBC);
            fB1 = *(const float4*)(pBC + 64);
            fC0 = *(const float4*)(pBC + 128);
            fC1 = *(const float4*)(pBC + 192);
        }

        float dl[4] = {cD.x, cD.y, cD.z, cD.w};
        float dx[4] = {cD.x * cX.x, cD.y * cX.y, cD.z * cX.z, cD.w * cX.w};
        float bv[8] = {cB0.x,cB0.y,cB0.z,cB0.w,cB1.x,cB1.y,cB1.z,cB1.w};
        float cv[8] = {cC0.x,cC0.y,cC0.z,cC0.w,cC1.x,cC1.y,cC1.z,cC1.w};

        float accd[4] = {0.f, 0.f, 0.f, 0.f};
        #pragma unroll
        for (int dd = 0; dd < 4; dd++) {
            if (UNI) {
                float dA = __expf(dl[dd] * a[dd][0]);
                #pragma unroll
                for (int j = 0; j < 8; j++) {
                    h[dd][j] = fmaf(dA, h[dd][j], dx[dd] * bv[j]);
                    accd[dd] = fmaf(cv[j], h[dd][j], accd[dd]);
                }
            } else {
                #pragma unroll
                for (int j = 0; j < 8; j++) {
                    float dA = __expf(dl[dd] * a[dd][j]);
                    h[dd][j] = fmaf(dA, h[dd][j], dx[dd] * bv[j]);
                    accd[dd] = fmaf(cv[j], h[dd][j], accd[dd]);
                }
            }
        }
        #pragma unroll
        for (int dd = 0; dd < 4; dd++) {
            float v = accd[dd];
            v += __shfl_xor(v, 1);
            v += __shfl_xor(v, 2);
            v += __shfl_xor(v, 4);
            v += __shfl_xor(v, 8);
            accd[dd] = v;
        }
        if (sub == 0) {
            float4 o4 = make_float4(accd[0], accd[1], accd[2], accd[3]);
            *(float4*)pO = o4;
        }
        pO += 256;
    }
}

__global__ __launch_bounds__(256)
void scan_k(const float* __restrict__ dBC,   // [8704,512] delta|Bm|Cm
            const float* __restrict__ Xc,    // [8704,256]
            const float* __restrict__ A,     // [256,128]
            float* __restrict__ XS)          // [8704,256]
{
    const int b  = blockIdx.y;
    const int d0 = blockIdx.x * 64;
    const int tid = threadIdx.x;
    const int sub = tid & 15;
    const int pg  = tid >> 4;
    const int dbase = d0 + pg * 4;
    const int nA = sub * 4;

    float a[4][8], h[4][8];
    bool uni = true;
    #pragma unroll
    for (int dd = 0; dd < 4; dd++) {
        const float* Ar = A + (size_t)(dbase + dd) * NN;
        float4 q0 = *(const float4*)(Ar + nA);
        float4 q1 = *(const float4*)(Ar + 64 + nA);
        a[dd][0]=q0.x; a[dd][1]=q0.y; a[dd][2]=q0.z; a[dd][3]=q0.w;
        a[dd][4]=q1.x; a[dd][5]=q1.y; a[dd][6]=q1.z; a[dd][7]=q1.w;
        #pragma unroll
        for (int j = 0; j < 8; j++) { h[dd][j] = 0.f; uni &= (a[dd][j] == a[dd][0]); }
    }

    const float* pD  = dBC + (size_t)b * LL * 512 + dbase;
    const float* pBC = dBC + (size_t)b * LL * 512 + 256 + nA;
    const float* pX  = Xc  + (size_t)b * LL * 256 + dbase;
    float*       pO  = XS  + (size_t)b * LL * 256 + dbase;

    if (uni) scan_loop<true >(pD, pBC, pX, pO, a, h, sub);
    else     scan_loop<false>(pD, pBC, pX, pO, a, h, sub);
}

// ---------------------------------------------------------------------------
// FNN stage 1: partials[kc][b][o] = F[b, kc*256..+255] @ W1T[kc*256..+255, o]
// grid (16 btiles, 17 kchunks), 256 threads: o = tid&63, bq = tid>>6 (4 b's).
// Deterministic (no atomics): each block owns its [kc][16 b] slice.
// ---------------------------------------------------------------------------
__global__ __launch_bounds__(256)
void fnn1_k(const float* __restrict__ F, const float* __restrict__ W1T,
            float* __restrict__ partials)
{
    const int btile = blockIdx.x;
    const int kc    = blockIdx.y;
    const int tid   = threadIdx.x;
    __shared__ float sf[16][260];
    for (int i = tid; i < 16 * 256; i += 256) {
        int r = i >> 8, c = i & 255;
        sf[r][c] = F[(size_t)(btile * 16 + r) * 4352 + kc * 256 + c];
    }
    __syncthreads();

    const int o  = tid & 63;
    const int bq = tid >> 6;
    const float* w = W1T + (size_t)(kc * 256) * 64 + o;
    float acc[4] = {0.f, 0.f, 0.f, 0.f};
    for (int k = 0; k < 256; k += 4) {
        float w0 = w[(size_t)(k + 0) * 64];
        float w1 = w[(size_t)(k + 1) * 64];
        float w2 = w[(size_t)(k + 2) * 64];
        float w3 = w[(size_t)(k + 3) * 64];
        #pragma unroll
        for (int bj = 0; bj < 4; bj++) {
            float4 f4 = *(const float4*)&sf[bq * 4 + bj][k];
            acc[bj] = fmaf(w0, f4.x, acc[bj]);
            acc[bj] = fmaf(w1, f4.y, acc[bj]);
            acc[bj] = fmaf(w2, f4.z, acc[bj]);
            acc[bj] = fmaf(w3, f4.w, acc[bj]);
        }
    }
    #pragma unroll
    for (int bj = 0; bj < 4; bj++)
        partials[(size_t)kc * 16384 + (btile * 16 + bq * 4 + bj) * 64 + o] = acc[bj];
}

// ---------------------------------------------------------------------------
// FNN stage 2: reduce 17 partials, leaky, then @fnn2_w.T + b2 -> out[b][32].
// One block per b, 64 threads.
// ---------------------------------------------------------------------------
__global__ __launch_bounds__(64)
void fnn2_k(const float* __restrict__ partials,
            const float* __restrict__ B1,
            const float* __restrict__ W2, const float* __restrict__ B2,
            float* __restrict__ out)
{
    int b = blockIdx.x;
    int t = threadIdx.x;
    __shared__ float s1[64];
    float acc = B1[t];
    #pragma unroll
    for (int kc = 0; kc < 17; kc++)
        acc += partials[(size_t)kc * 16384 + b * 64 + t];
    s1[t] = leaky_f(acc);
    __syncthreads();

    if (t < 32) {
        float acc2 = B2[t];
        const float* w2 = W2 + t * 64;
        #pragma unroll
        for (int j = 0; j < 64; j++) acc2 = fmaf(s1[j], w2[j], acc2);
        out[(size_t)b * 32 + t] = acc2;
    }
}

// ---------------------------------------------------------------------------
extern "C" void kernel_launch(void* const* d_in, const int* in_sizes, int n_in,
                              void* d_out, int out_size, void* d_ws, size_t ws_size,
                              hipStream_t stream)
{
    const float* x        = (const float*)d_in[0];
    const float* conv_w   = (const float*)d_in[1];
    const float* conv_b   = (const float*)d_in[2];
    const float* norm_w   = (const float*)d_in[3];
    const float* inp_w    = (const float*)d_in[4];
    const float* inp_b    = (const float*)d_in[5];
    const float* seqconv_w= (const float*)d_in[6];
    const float* seqconv_b= (const float*)d_in[7];
    const float* convlin_w= (const float*)d_in[8];
    const float* convlin_b= (const float*)d_in[9];
    const float* fc1_w    = (const float*)d_in[10];
    const float* fc1_b    = (const float*)d_in[11];
    const float* fc2_w    = (const float*)d_in[12];
    const float* fc2_b    = (const float*)d_in[13];
    const float* fc3_w    = (const float*)d_in[14];
    const float* fc3_b    = (const float*)d_in[15];
    const float* A        = (const float*)d_in[16];
    const float* D_w      = (const float*)d_in[17];
    const float* D_b      = (const float*)d_in[18];
    const float* out_w    = (const float*)d_in[19];
    const float* out_b    = (const float*)d_in[20];
    const float* fnn1_w   = (const float*)d_in[21];
    const float* fnn1_b   = (const float*)d_in[22];
    const float* fnn2_w   = (const float*)d_in[23];
    const float* fnn2_b   = (const float*)d_in[24];

    float* ws    = (float*)d_ws;
    float* xn    = ws;                   // [8704,128]
    float* buf1  = ws + 1114112;         // [8704,512]  xp | dgate_pre
    float* xc    = ws + 5570560;         // [8704,256]  (reused as xs)
    float* xc2   = ws + 7798784;         // [8704,256]
    float* buf3  = ws + 10027008;        // [8704,512]  delta|Bm|Cm, later partials
    float* wcat1 = ws + 14483456;        // [512,128]
    float* wcat3 = ws + 14548992;        // [512,256]
    float* bias1 = ws + 14680064;        // [512]
    float* bias3 = ws + 14680576;        // [512]
    float* w1t   = ws + 14681088;        // [4352,64]
    float* xs    = xc;                   // xc dead after convlin GEMM
    float* fout  = xn;                   // xn dead after first GEMM
    float* partials = buf3;              // buf3 dead after scan_k

    prep_k<<<1088, 256, 0, stream>>>(inp_w, D_w, fc1_w, fc2_w, fc3_w,
                                     inp_b, D_b, fc1_b, fc2_b, fc3_b,
                                     fnn1_w, wcat1, wcat3, bias1, bias3, w1t);

    conv_norm_k<<<MM, 128, 0, stream>>>(x, conv_w, conv_b, norm_w, xn);

    // xp | dgate_pre = xn @ [inp_w;D_w].T + [inp_b|D_b]
    gemm_k<128, 0, 0><<<dim3(MM / 128, 8), 256, 0, stream>>>(
        xn, 128, nullptr, 0, wcat1, bias1, buf1, 512);

    seqconv_k<<<NB, 256, 0, stream>>>(buf1, 512, seqconv_w, seqconv_b, xc);

    // xc2 = xc @ convlin_w.T + convlin_b
    gemm_k<256, 0, 0><<<dim3(MM / 128, 4), 256, 0, stream>>>(
        xc, 256, nullptr, 0, convlin_w, convlin_b, xc2, 256);

    // delta|Bm|Cm = xc2 @ [fc1;fc2;fc3].T + bias (softplus on delta cols)
    gemm_k<256, 0, 1><<<dim3(MM / 128, 8), 256, 0, stream>>>(
        xc2, 256, nullptr, 0, wcat3, bias3, buf3, 512);

    scan_k<<<dim3(4, NB), 256, 0, stream>>>(buf3, xc2, A, xs);

    // fout = (silu(xs)*silu(dgate_pre)) @ out_w.T + out_b
    gemm_k<256, 1, 0><<<dim3(MM / 128, 2), 256, 0, stream>>>(
        xs, 256, buf1 + 256, 512, out_w, out_b, fout, 128);

    fnn1_k<<<dim3(16, 17), 256, 0, stream>>>(fout, w1t, partials);
    fnn2_k<<<NB, 64, 0, stream>>>(partials, fnn1_b, fnn2_w, fnn2_b,
                                  (float*)d_out);
}

// Round 4
// 328.331 us; speedup vs baseline: 1.2510x; 1.0021x over previous
//
#include <hip/hip_runtime.h>
#include <math.h>

// ---------------------------------------------------------------------------
// SpectralGroupAttention: conv1d+leaky+rmsnorm -> GEMM(inp|D) -> seqconv+silu
// -> GEMM(convlin) -> GEMM(fc1|fc2|fc3, softplus on delta) -> fused S6 scan
// -> GEMM(out_w, gated prologue) -> split-K FNN head.
// All fp32. B=256, L=34, d=128, di=256, N=128, M=8704.
// ---------------------------------------------------------------------------

#define NB    256
#define LL    34
#define DD    128
#define DI    256
#define NN    128
#define MM    (NB*LL)       // 8704

__device__ __forceinline__ float silu_f(float x)  { return x / (1.f + __expf(-x)); }
// fast softplus: __logf/__expf are native v_log/v_exp (2 instrs each); the
// precise log1pf/exp2f OCML paths are ~8 instrs and showed up as VALU bloat.
__device__ __forceinline__ float softplus_f(float x) {
    return fmaxf(x, 0.f) + __logf(1.f + __expf(-fabsf(x)));
}
__device__ __forceinline__ float leaky_f(float x) { return (x >= 0.f) ? x : 0.01f * x; }

// ---------------------------------------------------------------------------
// prep: concat weights/biases + transpose fnn1_w -> W1T[4352][64].
// grid 1088 x 256 covers 278528 items.
// ---------------------------------------------------------------------------
__global__ void prep_k(const float* __restrict__ inp_w, const float* __restrict__ D_w,
                       const float* __restrict__ fc1_w, const float* __restrict__ fc2_w,
                       const float* __restrict__ fc3_w,
                       const float* __restrict__ inp_b, const float* __restrict__ D_b,
                       const float* __restrict__ fc1_b, const float* __restrict__ fc2_b,
                       const float* __restrict__ fc3_b,
                       const float* __restrict__ W1,
                       float* __restrict__ wcat1, float* __restrict__ wcat3,
                       float* __restrict__ bias1, float* __restrict__ bias3,
                       float* __restrict__ W1T)
{
    int i = blockIdx.x * 256 + threadIdx.x;
    if (i < 65536)  wcat1[i] = (i < 32768) ? inp_w[i] : D_w[i - 32768];
    if (i < 131072) wcat3[i] = (i < 65536) ? fc1_w[i]
                              : (i < 98304 ? fc2_w[i - 65536] : fc3_w[i - 98304]);
    if (i < 278528) W1T[i] = W1[(size_t)(i & 63) * 4352 + (i >> 6)];
    if (i < 512) {
        bias1[i] = (i < 256) ? inp_b[i] : D_b[i - 256];
        bias3[i] = (i < 256) ? fc1_b[i] : (i < 384 ? fc2_b[i - 256] : fc3_b[i - 384]);
    }
}

// ---------------------------------------------------------------------------
// conv1d(1->128, k=20, stride=5) + bias + leaky, then RMSNorm over d=128.
// One block per (b,l) row, 128 threads (= channels).
// ---------------------------------------------------------------------------
__global__ __launch_bounds__(128)
void conv_norm_k(const float* __restrict__ x, const float* __restrict__ cw,
                 const float* __restrict__ cb, const float* __restrict__ nw,
                 float* __restrict__ XN)
{
    int bl = blockIdx.x;             // b*34 + l
    int b = bl / LL, l = bl % LL;
    int c = threadIdx.x;
    const float* xr = x + (size_t)b * 189 + l * 5;   // wave-uniform base
    float g = cb[c];
    #pragma unroll
    for (int k = 0; k < 20; k++) g = fmaf(xr[k], cw[c * 20 + k], g);
    g = leaky_f(g);

    float s = g * g;
    #pragma unroll
    for (int m = 32; m >= 1; m >>= 1) s += __shfl_xor(s, m);
    __shared__ float wsum[2];
    if ((threadIdx.x & 63) == 0) wsum[threadIdx.x >> 6] = s;
    __syncthreads();
    float mean = (wsum[0] + wsum[1]) * (1.f / 128.f);
    float inv = 1.f / sqrtf(mean + 1e-5f);
    XN[(size_t)bl * DD + c] = g * inv * nw[c];
}

// ---------------------------------------------------------------------------
// Tiled fp32 GEMM: Y[r,c] = epi( sum_k A(r,k) * W[c,k] + bias[c] )
// BM=128, BN=64, 256 threads, micro 8x4, K-chunk 16.  M must be %128==0.
// PROLOG: 0 -> a = X[r,k];  1 -> a = silu(X[r,k]) * silu(X2[r,k])   (gate)
// EPI:    0 -> none;        1 -> softplus for cols < 256            (delta)
// ---------------------------------------------------------------------------
template <int K, int PROLOG, int EPI>
__global__ __launch_bounds__(256)
void gemm_k(const float* __restrict__ X, int ldx,
            const float* __restrict__ X2, int ldx2,
            const float* __restrict__ W, const float* __restrict__ bias,
            float* __restrict__ Y, int ldy)
{
    const int tid = threadIdx.x;
    const int r0 = blockIdx.x * 128;
    const int c0 = blockIdx.y * 64;
    __shared__ float As[16][132];
    __shared__ float Bs[16][68];

    const int tx = tid & 15;          // 0..15 -> 4 cols
    const int ty = tid >> 4;          // 0..15 -> 8 rows

    float acc[8][4];
    #pragma unroll
    for (int i = 0; i < 8; i++)
        #pragma unroll
        for (int j = 0; j < 4; j++) acc[i][j] = 0.f;

    const int a_r = tid >> 1, a_k = (tid & 1) * 8;       // A loader: 8 floats
    const int b_c = tid >> 2, b_k = (tid & 3) * 4;       // B loader: 4 floats

    for (int k0 = 0; k0 < K; k0 += 16) {
        // ---- stage A tile (transposed to As[k][r]) ----
        const float* xp = X + (size_t)(r0 + a_r) * ldx + k0 + a_k;
        float av[8];
        float4 v0 = *(const float4*)(xp);
        float4 v1 = *(const float4*)(xp + 4);
        av[0]=v0.x; av[1]=v0.y; av[2]=v0.z; av[3]=v0.w;
        av[4]=v1.x; av[5]=v1.y; av[6]=v1.z; av[7]=v1.w;
        if (PROLOG == 1) {
            const float* xq = X2 + (size_t)(r0 + a_r) * ldx2 + k0 + a_k;
            float4 w0 = *(const float4*)(xq);
            float4 w1 = *(const float4*)(xq + 4);
            float g2[8] = {w0.x,w0.y,w0.z,w0.w,w1.x,w1.y,w1.z,w1.w};
            #pragma unroll
            for (int j = 0; j < 8; j++) av[j] = silu_f(av[j]) * silu_f(g2[j]);
        }
        #pragma unroll
        for (int j = 0; j < 8; j++) As[a_k + j][a_r] = av[j];

        // ---- stage B tile (transposed to Bs[k][c]) ----
        float4 wv = *(const float4*)(W + (size_t)(c0 + b_c) * K + k0 + b_k);
        Bs[b_k + 0][b_c] = wv.x; Bs[b_k + 1][b_c] = wv.y;
        Bs[b_k + 2][b_c] = wv.z; Bs[b_k + 3][b_c] = wv.w;

        __syncthreads();
        #pragma unroll
        for (int kk = 0; kk < 16; kk++) {
            float4 a0 = *(const float4*)&As[kk][ty * 8];
            float4 a1 = *(const float4*)&As[kk][ty * 8 + 4];
            float4 b0 = *(const float4*)&Bs[kk][tx * 4];
            float avv[8] = {a0.x,a0.y,a0.z,a0.w,a1.x,a1.y,a1.z,a1.w};
            float bvv[4] = {b0.x,b0.y,b0.z,b0.w};
            #pragma unroll
            for (int i = 0; i < 8; i++)
                #pragma unroll
                for (int j = 0; j < 4; j++)
                    acc[i][j] = fmaf(avv[i], bvv[j], acc[i][j]);
        }
        __syncthreads();
    }

    const bool do_sp = (EPI == 1) && (c0 < 256);
    #pragma unroll
    for (int i = 0; i < 8; i++) {
        int r = r0 + ty * 8 + i;
        float4 o;
        o.x = acc[i][0] + bias[c0 + tx * 4 + 0];
        o.y = acc[i][1] + bias[c0 + tx * 4 + 1];
        o.z = acc[i][2] + bias[c0 + tx * 4 + 2];
        o.w = acc[i][3] + bias[c0 + tx * 4 + 3];
        if (do_sp) {
            o.x = softplus_f(o.x); o.y = softplus_f(o.y);
            o.z = softplus_f(o.z); o.w = softplus_f(o.w);
        }
        *(float4*)&Y[(size_t)r * ldy + c0 + tx * 4] = o;
    }
}

// ---------------------------------------------------------------------------
// seqconv: Conv1d over L as channels (34->34, k=3, pad=1 on the di axis)
// + bias + silu.  One block per b, 256 threads.
// All weights staged in LDS (transposed) -- the previous version read them
// through wave-uniform global pointers => s_load chains => 91% VALU idle.
// Thread (ty = wave 0..3, tx = 0..63): 4 j's (j0 = tx*4) x lo-set(ty).
// lo-sets: {0-8, 9-17, 18-25, 26-33}; weight LDS reads are wave-uniform
// broadcasts (conflict-free).
// ---------------------------------------------------------------------------
__global__ __launch_bounds__(256)
void seqconv_k(const float* __restrict__ XP, int ldxp,
               const float* __restrict__ w, const float* __restrict__ bias,
               float* __restrict__ XC)
{
    const int b   = blockIdx.x;
    const int tid = threadIdx.x;
    const int tx  = tid & 63;
    const int ty  = tid >> 6;
    const int j0  = tx * 4;

    __shared__ float sx[LL][264];    // sx[li][j+1]; 264 keeps rows 16B-aligned
    __shared__ float sw[LL][112];    // sw[li][lo*3+k]

    // stage x: 34*256 loads, coalesced
    for (int idx = tid; idx < LL * 256; idx += 256) {
        int li = idx >> 8, jj = idx & 255;
        sx[li][jj + 1] = XP[(size_t)(b * LL + li) * ldxp + jj];
    }
    if (tid < LL) { sx[tid][0] = 0.f; sx[tid][257] = 0.f; }
    // stage weights transposed: w[lo*102 + li*3 + k] -> sw[li][lo*3+k]
    for (int idx = tid; idx < LL * LL * 3; idx += 256) {
        int lo = idx / 102;
        int rem = idx - lo * 102;
        int li = rem / 3;
        int k  = rem - li * 3;
        sw[li][lo * 3 + k] = w[idx];
    }
    __syncthreads();

    const int base = ty * 9 - (ty == 3 ? 1 : 0);   // 0,9,18,26
    const int cnt  = (ty < 2) ? 9 : 8;

    float acc[9][4];
    #pragma unroll
    for (int i = 0; i < 9; i++)
        #pragma unroll
        for (int jj = 0; jj < 4; jj++) acc[i][jj] = 0.f;

    for (int li = 0; li < LL; li++) {
        float4 xa = *(const float4*)&sx[li][j0];       // j0-1 .. j0+2
        float2 xb = *(const float2*)&sx[li][j0 + 4];   // j0+3, j0+4
        float xv[6] = {xa.x, xa.y, xa.z, xa.w, xb.x, xb.y};
        const float* swr = &sw[li][0];
        #pragma unroll
        for (int i = 0; i < 9; i++) {
            if (i < cnt) {                              // wave-uniform guard
                int lo3 = (base + i) * 3;
                float w0 = swr[lo3 + 0];
                float w1 = swr[lo3 + 1];
                float w2 = swr[lo3 + 2];
                #pragma unroll
                for (int jj = 0; jj < 4; jj++) {
                    acc[i][jj] = fmaf(w0, xv[jj],     acc[i][jj]);
                    acc[i][jj] = fmaf(w1, xv[jj + 1], acc[i][jj]);
                    acc[i][jj] = fmaf(w2, xv[jj + 2], acc[i][jj]);
                }
            }
        }
    }

    #pragma unroll
    for (int i = 0; i < 9; i++) {
        if (i < cnt) {
            int lo = base + i;
            float bb = bias[lo];
            float4 o;
            o.x = silu_f(acc[i][0] + bb);
            o.y = silu_f(acc[i][1] + bb);
            o.z = silu_f(acc[i][2] + bb);
            o.w = silu_f(acc[i][3] + bb);
            *(float4*)&XC[(size_t)(b * LL + lo) * DI + j0] = o;
        }
    }
}

// ---------------------------------------------------------------------------
// Fused S6 scan, LDS-free.  Block = (b, 32 d's): grid (8, NB) = 2048 blocks
// for full occupancy.  256 threads: sub = tid&15 owns n in {sub*4..+3} u
// {64+sub*4..+3};  pg = tid>>4 owns d = d0+pg*2..+1.  h[2][8] in regs;
// next-l fragments register-prefetched through walking pointers.
// UNI fast path: when A[d,n] is constant along n for this thread's rows
// (true for the given A = ones/sqrt(N)), one exp per (l,d) instead of 8.
// ---------------------------------------------------------------------------
template <bool UNI>
__device__ __forceinline__ void scan_loop(
    const float* __restrict__ pD,    // walks b*LL*512 + dbase, stride 512
    const float* __restrict__ pBC,   // walks b*LL*512 + 256 + nA, stride 512
    const float* __restrict__ pX,    // walks b*LL*256 + dbase, stride 256
    float* __restrict__ pO,          // walks b*LL*256 + dbase, stride 256
    float a[2][8], float h[2][8], int sub)
{
    float2 fD  = *(const float2*)(pD);
    float2 fX  = *(const float2*)(pX);
    float4 fB0 = *(const float4*)(pBC);
    float4 fB1 = *(const float4*)(pBC + 64);
    float4 fC0 = *(const float4*)(pBC + 128);
    float4 fC1 = *(const float4*)(pBC + 192);

    for (int l = 0; l < LL; l++) {
        float2 cD = fD, cX = fX;
        float4 cB0 = fB0, cB1 = fB1, cC0 = fC0, cC1 = fC1;
        pD += 512; pBC += 512; pX += 256;
        if (l + 1 < LL) {
            fD  = *(const float2*)(pD);
            fX  = *(const float2*)(pX);
            fB0 = *(const float4*)(pBC);
            fB1 = *(const float4*)(pBC + 64);
            fC0 = *(const float4*)(pBC + 128);
            fC1 = *(const float4*)(pBC + 192);
        }

        float dl[2] = {cD.x, cD.y};
        float dx[2] = {cD.x * cX.x, cD.y * cX.y};
        float bv[8] = {cB0.x,cB0.y,cB0.z,cB0.w,cB1.x,cB1.y,cB1.z,cB1.w};
        float cv[8] = {cC0.x,cC0.y,cC0.z,cC0.w,cC1.x,cC1.y,cC1.z,cC1.w};

        float accd[2] = {0.f, 0.f};
        #pragma unroll
        for (int dd = 0; dd < 2; dd++) {
            if (UNI) {
                float dA = __expf(dl[dd] * a[dd][0]);
                #pragma unroll
                for (int j = 0; j < 8; j++) {
                    h[dd][j] = fmaf(dA, h[dd][j], dx[dd] * bv[j]);
                    accd[dd] = fmaf(cv[j], h[dd][j], accd[dd]);
                }
            } else {
                #pragma unroll
                for (int j = 0; j < 8; j++) {
                    float dA = __expf(dl[dd] * a[dd][j]);
                    h[dd][j] = fmaf(dA, h[dd][j], dx[dd] * bv[j]);
                    accd[dd] = fmaf(cv[j], h[dd][j], accd[dd]);
                }
            }
        }
        #pragma unroll
        for (int dd = 0; dd < 2; dd++) {
            float v = accd[dd];
            v += __shfl_xor(v, 1);
            v += __shfl_xor(v, 2);
            v += __shfl_xor(v, 4);
            v += __shfl_xor(v, 8);
            accd[dd] = v;
        }
        if (sub == 0) {
            float2 o2 = make_float2(accd[0], accd[1]);
            *(float2*)pO = o2;
        }
        pO += 256;
    }
}

__global__ __launch_bounds__(256)
void scan_k(const float* __restrict__ dBC,   // [8704,512] delta|Bm|Cm
            const float* __restrict__ Xc,    // [8704,256]
            const float* __restrict__ A,     // [256,128]
            float* __restrict__ XS)          // [8704,256]
{
    const int b  = blockIdx.y;
    const int d0 = blockIdx.x * 32;
    const int tid = threadIdx.x;
    const int sub = tid & 15;
    const int pg  = tid >> 4;
    const int dbase = d0 + pg * 2;
    const int nA = sub * 4;

    float a[2][8], h[2][8];
    bool uni = true;
    #pragma unroll
    for (int dd = 0; dd < 2; dd++) {
        const float* Ar = A + (size_t)(dbase + dd) * NN;
        float4 q0 = *(const float4*)(Ar + nA);
        float4 q1 = *(const float4*)(Ar + 64 + nA);
        a[dd][0]=q0.x; a[dd][1]=q0.y; a[dd][2]=q0.z; a[dd][3]=q0.w;
        a[dd][4]=q1.x; a[dd][5]=q1.y; a[dd][6]=q1.z; a[dd][7]=q1.w;
        #pragma unroll
        for (int j = 0; j < 8; j++) { h[dd][j] = 0.f; uni &= (a[dd][j] == a[dd][0]); }
    }

    const float* pD  = dBC + (size_t)b * LL * 512 + dbase;
    const float* pBC = dBC + (size_t)b * LL * 512 + 256 + nA;
    const float* pX  = Xc  + (size_t)b * LL * 256 + dbase;
    float*       pO  = XS  + (size_t)b * LL * 256 + dbase;

    if (uni) scan_loop<true >(pD, pBC, pX, pO, a, h, sub);
    else     scan_loop<false>(pD, pBC, pX, pO, a, h, sub);
}

// ---------------------------------------------------------------------------
// FNN stage 1: partials[kc][b][o] = F[b, kc*256..+255] @ W1T[kc*256..+255, o]
// grid (16 btiles, 17 kchunks), 256 threads: o = tid&63, bq = tid>>6 (4 b's).
// Deterministic (no atomics): each block owns its [kc][16 b] slice.
// ---------------------------------------------------------------------------
__global__ __launch_bounds__(256)
void fnn1_k(const float* __restrict__ F, const float* __restrict__ W1T,
            float* __restrict__ partials)
{
    const int btile = blockIdx.x;
    const int kc    = blockIdx.y;
    const int tid   = threadIdx.x;
    __shared__ float sf[16][260];
    for (int i = tid; i < 16 * 256; i += 256) {
        int r = i >> 8, c = i & 255;
        sf[r][c] = F[(size_t)(btile * 16 + r) * 4352 + kc * 256 + c];
    }
    __syncthreads();

    const int o  = tid & 63;
    const int bq = tid >> 6;
    const float* w = W1T + (size_t)(kc * 256) * 64 + o;
    float acc[4] = {0.f, 0.f, 0.f, 0.f};
    for (int k = 0; k < 256; k += 4) {
        float w0 = w[(size_t)(k + 0) * 64];
        float w1 = w[(size_t)(k + 1) * 64];
        float w2 = w[(size_t)(k + 2) * 64];
        float w3 = w[(size_t)(k + 3) * 64];
        #pragma unroll
        for (int bj = 0; bj < 4; bj++) {
            float4 f4 = *(const float4*)&sf[bq * 4 + bj][k];
            acc[bj] = fmaf(w0, f4.x, acc[bj]);
            acc[bj] = fmaf(w1, f4.y, acc[bj]);
            acc[bj] = fmaf(w2, f4.z, acc[bj]);
            acc[bj] = fmaf(w3, f4.w, acc[bj]);
        }
    }
    #pragma unroll
    for (int bj = 0; bj < 4; bj++)
        partials[(size_t)kc * 16384 + (btile * 16 + bq * 4 + bj) * 64 + o] = acc[bj];
}

// ---------------------------------------------------------------------------
// FNN stage 2: reduce 17 partials, leaky, then @fnn2_w.T + b2 -> out[b][32].
// One block per b, 64 threads.
// ---------------------------------------------------------------------------
__global__ __launch_bounds__(64)
void fnn2_k(const float* __restrict__ partials,
            const float* __restrict__ B1,
            const float* __restrict__ W2, const float* __restrict__ B2,
            float* __restrict__ out)
{
    int b = blockIdx.x;
    int t = threadIdx.x;
    __shared__ float s1[64];
    float acc = B1[t];
    #pragma unroll
    for (int kc = 0; kc < 17; kc++)
        acc += partials[(size_t)kc * 16384 + b * 64 + t];
    s1[t] = leaky_f(acc);
    __syncthreads();

    if (t < 32) {
        float acc2 = B2[t];
        const float* w2 = W2 + t * 64;
        #pragma unroll
        for (int j = 0; j < 64; j++) acc2 = fmaf(s1[j], w2[j], acc2);
        out[(size_t)b * 32 + t] = acc2;
    }
}

// ---------------------------------------------------------------------------
extern "C" void kernel_launch(void* const* d_in, const int* in_sizes, int n_in,
                              void* d_out, int out_size, void* d_ws, size_t ws_size,
                              hipStream_t stream)
{
    const float* x        = (const float*)d_in[0];
    const float* conv_w   = (const float*)d_in[1];
    const float* conv_b   = (const float*)d_in[2];
    const float* norm_w   = (const float*)d_in[3];
    const float* inp_w    = (const float*)d_in[4];
    const float* inp_b    = (const float*)d_in[5];
    const float* seqconv_w= (const float*)d_in[6];
    const float* seqconv_b= (const float*)d_in[7];
    const float* convlin_w= (const float*)d_in[8];
    const float* convlin_b= (const float*)d_in[9];
    const float* fc1_w    = (const float*)d_in[10];
    const float* fc1_b    = (const float*)d_in[11];
    const float* fc2_w    = (const float*)d_in[12];
    const float* fc2_b    = (const float*)d_in[13];
    const float* fc3_w    = (const float*)d_in[14];
    const float* fc3_b    = (const float*)d_in[15];
    const float* A        = (const float*)d_in[16];
    const float* D_w      = (const float*)d_in[17];
    const float* D_b      = (const float*)d_in[18];
    const float* out_w    = (const float*)d_in[19];
    const float* out_b    = (const float*)d_in[20];
    const float* fnn1_w   = (const float*)d_in[21];
    const float* fnn1_b   = (const float*)d_in[22];
    const float* fnn2_w   = (const float*)d_in[23];
    const float* fnn2_b   = (const float*)d_in[24];

    float* ws    = (float*)d_ws;
    float* xn    = ws;                   // [8704,128]
    float* buf1  = ws + 1114112;         // [8704,512]  xp | dgate_pre
    float* xc    = ws + 5570560;         // [8704,256]  (reused as xs)
    float* xc2   = ws + 7798784;         // [8704,256]
    float* buf3  = ws + 10027008;        // [8704,512]  delta|Bm|Cm, later partials
    float* wcat1 = ws + 14483456;        // [512,128]
    float* wcat3 = ws + 14548992;        // [512,256]
    float* bias1 = ws + 14680064;        // [512]
    float* bias3 = ws + 14680576;        // [512]
    float* w1t   = ws + 14681088;        // [4352,64]
    float* xs    = xc;                   // xc dead after convlin GEMM
    float* fout  = xn;                   // xn dead after first GEMM
    float* partials = buf3;              // buf3 dead after scan_k

    prep_k<<<1088, 256, 0, stream>>>(inp_w, D_w, fc1_w, fc2_w, fc3_w,
                                     inp_b, D_b, fc1_b, fc2_b, fc3_b,
                                     fnn1_w, wcat1, wcat3, bias1, bias3, w1t);

    conv_norm_k<<<MM, 128, 0, stream>>>(x, conv_w, conv_b, norm_w, xn);

    // xp | dgate_pre = xn @ [inp_w;D_w].T + [inp_b|D_b]
    gemm_k<128, 0, 0><<<dim3(MM / 128, 8), 256, 0, stream>>>(
        xn, 128, nullptr, 0, wcat1, bias1, buf1, 512);

    seqconv_k<<<NB, 256, 0, stream>>>(buf1, 512, seqconv_w, seqconv_b, xc);

    // xc2 = xc @ convlin_w.T + convlin_b
    gemm_k<256, 0, 0><<<dim3(MM / 128, 4), 256, 0, stream>>>(
        xc, 256, nullptr, 0, convlin_w, convlin_b, xc2, 256);

    // delta|Bm|Cm = xc2 @ [fc1;fc2;fc3].T + bias (softplus on delta cols)
    gemm_k<256, 0, 1><<<dim3(MM / 128, 8), 256, 0, stream>>>(
        xc2, 256, nullptr, 0, wcat3, bias3, buf3, 512);

    scan_k<<<dim3(8, NB), 256, 0, stream>>>(buf3, xc2, A, xs);

    // fout = (silu(xs)*silu(dgate_pre)) @ out_w.T + out_b
    gemm_k<256, 1, 0><<<dim3(MM / 128, 2), 256, 0, stream>>>(
        xs, 256, buf1 + 256, 512, out_w, out_b, fout, 128);

    fnn1_k<<<dim3(16, 17), 256, 0, stream>>>(fout, w1t, partials);
    fnn2_k<<<NB, 64, 0, stream>>>(partials, fnn1_b, fnn2_w, fnn2_b,
                                  (float*)d_out);
}

// Round 5
// 289.674 us; speedup vs baseline: 1.4180x; 1.1335x over previous
//
#include <hip/hip_runtime.h>
#include <math.h>

// ---------------------------------------------------------------------------
// SpectralGroupAttention: conv1d+leaky+rmsnorm -> MFMA-GEMM(inp|D) -> seqconv
// -> MFMA-GEMM(convlin) -> MFMA-GEMM(fc1|2|3, softplus) -> fused S6 scan
// (+gate epilogue) -> MFMA-GEMM(out_w) -> split-K FNN head.
// GEMMs use split-bf16 (hi+lo, 3 MFMA products) => fp32-level accuracy at
// bf16 MFMA rates.  B=256, L=34, d=128, di=256, N=128, M=8704.
// ---------------------------------------------------------------------------

#define NB    256
#define LL    34
#define DD    128
#define DI    256
#define NN    128
#define MM    (NB*LL)       // 8704

using u16 = unsigned short;
typedef __attribute__((ext_vector_type(8))) short short8;
typedef __attribute__((ext_vector_type(4))) float f32x4;

__device__ __forceinline__ float silu_f(float x)  { return x / (1.f + __expf(-x)); }
__device__ __forceinline__ float softplus_f(float x) {
    return fmaxf(x, 0.f) + __logf(1.f + __expf(-fabsf(x)));
}
__device__ __forceinline__ float leaky_f(float x) { return (x >= 0.f) ? x : 0.01f * x; }

__device__ __forceinline__ u16 f2bf(float x) {            // RNE fp32->bf16
    unsigned u = __float_as_uint(x);
    return (u16)((u + 0x7FFF + ((u >> 16) & 1)) >> 16);
}
__device__ __forceinline__ float bf2f(u16 h) {
    return __uint_as_float(((unsigned)h) << 16);
}
__device__ __forceinline__ void f2pair(float v, u16* h, u16* l) {
    u16 hh = f2bf(v);
    *h = hh;
    *l = f2bf(v - bf2f(hh));
}

// ---------------------------------------------------------------------------
// prep_w: convert all GEMM weights to bf16 hi/lo pairs + concat biases.
// wc1[512][128] = [inp_w;D_w]; wc3[512][256] = [fc1;fc2;fc3]; cv[256][256];
// ow[128][256].  294912 weight elems + 1024 biases -> grid 1152 x 256.
// ---------------------------------------------------------------------------
__global__ void prep_w_k(const float* __restrict__ inp_w, const float* __restrict__ D_w,
                         const float* __restrict__ fc1_w, const float* __restrict__ fc2_w,
                         const float* __restrict__ fc3_w, const float* __restrict__ convlin_w,
                         const float* __restrict__ out_w,
                         const float* __restrict__ inp_b, const float* __restrict__ D_b,
                         const float* __restrict__ fc1_b, const float* __restrict__ fc2_b,
                         const float* __restrict__ fc3_b,
                         u16* __restrict__ wc1h, u16* __restrict__ wc1l,
                         u16* __restrict__ wc3h, u16* __restrict__ wc3l,
                         u16* __restrict__ cvh,  u16* __restrict__ cvl,
                         u16* __restrict__ owh,  u16* __restrict__ owl,
                         float* __restrict__ bias1, float* __restrict__ bias3)
{
    int i = blockIdx.x * 256 + threadIdx.x;
    if (i < 65536) {
        float v = (i < 32768) ? inp_w[i] : D_w[i - 32768];
        f2pair(v, &wc1h[i], &wc1l[i]);
    } else if (i < 196608) {
        int j = i - 65536;
        float v = (j < 65536) ? fc1_w[j] : (j < 98304 ? fc2_w[j - 65536] : fc3_w[j - 98304]);
        f2pair(v, &wc3h[j], &wc3l[j]);
    } else if (i < 262144) {
        int j = i - 196608;
        f2pair(convlin_w[j], &cvh[j], &cvl[j]);
    } else if (i < 294912) {
        int j = i - 262144;
        f2pair(out_w[j], &owh[j], &owl[j]);
    }
    if (i < 512)  bias1[i] = (i < 256) ? inp_b[i] : D_b[i - 256];
    else if (i < 1024) {
        int j = i - 512;
        bias3[j] = (j < 256) ? fc1_b[j] : (j < 384 ? fc2_b[j - 256] : fc3_b[j - 384]);
    }
}

// ---------------------------------------------------------------------------
// transpose fnn1_w [64][4352] -> W1T [4352][64] via coalesced LDS tiles.
// grid 68 blocks, each handles 64 source-columns.
// ---------------------------------------------------------------------------
__global__ __launch_bounds__(256)
void transpose_k(const float* __restrict__ W1, float* __restrict__ W1T)
{
    __shared__ float tile[64][65];
    const int bx = blockIdx.x;          // col tile: bx*64 .. +63
    const int tid = threadIdx.x;
    for (int p = 0; p < 16; p++) {
        int idx = tid + p * 256;
        int r = idx >> 6, c = idx & 63;
        tile[r][c] = W1[(size_t)r * 4352 + bx * 64 + c];
    }
    __syncthreads();
    for (int p = 0; p < 16; p++) {
        int idx = tid + p * 256;
        int cc = idx >> 6, rr = idx & 63;
        W1T[(size_t)(bx * 64 + cc) * 64 + rr] = tile[rr][cc];
    }
}

// ---------------------------------------------------------------------------
// conv1d(1->128, k=20, stride=5) + bias + leaky, then RMSNorm over d=128.
// One block per (b,l) row, 128 threads; emits bf16 hi/lo pair.
// ---------------------------------------------------------------------------
__global__ __launch_bounds__(128)
void conv_norm_k(const float* __restrict__ x, const float* __restrict__ cw,
                 const float* __restrict__ cb, const float* __restrict__ nw,
                 u16* __restrict__ XNh, u16* __restrict__ XNl)
{
    int bl = blockIdx.x;             // b*34 + l
    int b = bl / LL, l = bl % LL;
    int c = threadIdx.x;
    const float* xr = x + (size_t)b * 189 + l * 5;
    float g = cb[c];
    #pragma unroll
    for (int k = 0; k < 20; k++) g = fmaf(xr[k], cw[c * 20 + k], g);
    g = leaky_f(g);

    float s = g * g;
    #pragma unroll
    for (int m = 32; m >= 1; m >>= 1) s += __shfl_xor(s, m);
    __shared__ float wsum[2];
    if ((threadIdx.x & 63) == 0) wsum[threadIdx.x >> 6] = s;
    __syncthreads();
    float mean = (wsum[0] + wsum[1]) * (1.f / 128.f);
    float inv = 1.f / sqrtf(mean + 1e-5f);
    float v = g * inv * nw[c];
    f2pair(v, &XNh[(size_t)bl * DD + c], &XNl[(size_t)bl * DD + c]);
}

// ---------------------------------------------------------------------------
// Split-bf16 MFMA GEMM: Y[r,c] = epi( X[r,:].Wt[c,:] + bias[c] ), where
// X ~ Ah+Al, W ~ Wh+Wl (bf16 hi/lo). 3 products: AhWh + AhWl + AlWh.
// Block 128(M)x64(N), 4 waves (wm=w&1: 64-row half, wn=w>>1: 32-col half),
// wave tile 64x32 = 4x2 tiles of 16x16, K-step 32 (mfma_f32_16x16x32_bf16).
// Layouts (HW-verified): A-frag A[m=lane&15][k=(lane>>4)*8+j];
// C/D col=lane&15, row=(lane>>4)*4+reg.
// EPI: 0 fp32 out; 1 fp32 out + softplus cols<256; 2 bf16-pair out.
// ---------------------------------------------------------------------------
template <int K, int EPI>
__global__ __launch_bounds__(256)
void mgemm_k(const u16* __restrict__ Ah, const u16* __restrict__ Al,
             const u16* __restrict__ Wh, const u16* __restrict__ Wl,
             const float* __restrict__ bias,
             float* __restrict__ Y, int ldy,
             u16* __restrict__ Yh, u16* __restrict__ Yl)
{
    const int tid  = threadIdx.x;
    const int r0   = blockIdx.x * 128;
    const int c0   = blockIdx.y * 64;
    const int wave = tid >> 6;
    const int lane = tid & 63;
    const int wm   = wave & 1;
    const int wn   = wave >> 1;
    const int l15  = lane & 15;
    const int lq   = lane >> 4;

    __shared__ u16 sAh[128][40];   // 40: 80B rows keep 16B align, banks ok
    __shared__ u16 sAl[128][40];
    __shared__ u16 sBh[64][40];
    __shared__ u16 sBl[64][40];

    f32x4 acc[4][2];
    #pragma unroll
    for (int i = 0; i < 4; i++)
        #pragma unroll
        for (int j = 0; j < 2; j++) acc[i][j] = (f32x4){0.f, 0.f, 0.f, 0.f};

    const int a_row = tid >> 1;              // 0..127
    const int a_kb  = (tid & 1) * 16;        // two 8-elem chunks at +0,+8
    const int b_row = tid >> 2;              // 0..63
    const int b_ko  = (tid & 3) * 8;

    for (int k0 = 0; k0 < K; k0 += 32) {
        const u16* ga = Ah + (size_t)(r0 + a_row) * K + k0 + a_kb;
        const u16* gl = Al + (size_t)(r0 + a_row) * K + k0 + a_kb;
        short8 vh0 = *(const short8*)(ga);
        short8 vh1 = *(const short8*)(ga + 8);
        short8 vl0 = *(const short8*)(gl);
        short8 vl1 = *(const short8*)(gl + 8);
        const u16* gb = Wh + (size_t)(c0 + b_row) * K + k0 + b_ko;
        const u16* gc = Wl + (size_t)(c0 + b_row) * K + k0 + b_ko;
        short8 wb = *(const short8*)(gb);
        short8 wc = *(const short8*)(gc);

        *(short8*)&sAh[a_row][a_kb]     = vh0;
        *(short8*)&sAh[a_row][a_kb + 8] = vh1;
        *(short8*)&sAl[a_row][a_kb]     = vl0;
        *(short8*)&sAl[a_row][a_kb + 8] = vl1;
        *(short8*)&sBh[b_row][b_ko] = wb;
        *(short8*)&sBl[b_row][b_ko] = wc;
        __syncthreads();

        short8 fah[4], fal[4], fbh[2], fbl[2];
        #pragma unroll
        for (int i = 0; i < 4; i++) {
            fah[i] = *(const short8*)&sAh[wm * 64 + i * 16 + l15][lq * 8];
            fal[i] = *(const short8*)&sAl[wm * 64 + i * 16 + l15][lq * 8];
        }
        #pragma unroll
        for (int j = 0; j < 2; j++) {
            fbh[j] = *(const short8*)&sBh[wn * 32 + j * 16 + l15][lq * 8];
            fbl[j] = *(const short8*)&sBl[wn * 32 + j * 16 + l15][lq * 8];
        }
        #pragma unroll
        for (int i = 0; i < 4; i++)
            #pragma unroll
            for (int j = 0; j < 2; j++) {
                acc[i][j] = __builtin_amdgcn_mfma_f32_16x16x32_bf16(fah[i], fbh[j], acc[i][j], 0, 0, 0);
                acc[i][j] = __builtin_amdgcn_mfma_f32_16x16x32_bf16(fah[i], fbl[j], acc[i][j], 0, 0, 0);
                acc[i][j] = __builtin_amdgcn_mfma_f32_16x16x32_bf16(fal[i], fbh[j], acc[i][j], 0, 0, 0);
            }
        __syncthreads();
    }

    #pragma unroll
    for (int i = 0; i < 4; i++) {
        int gr = r0 + wm * 64 + i * 16 + lq * 4;
        #pragma unroll
        for (int j = 0; j < 2; j++) {
            int gc = c0 + wn * 32 + j * 16 + l15;
            float bb = bias[gc];
            #pragma unroll
            for (int r = 0; r < 4; r++) {
                float v = acc[i][j][r] + bb;
                if (EPI == 1) { if (gc < 256) v = softplus_f(v); }
                if (EPI == 2) {
                    u16 hh, ll;
                    f2pair(v, &hh, &ll);
                    Yh[(size_t)(gr + r) * ldy + gc] = hh;
                    Yl[(size_t)(gr + r) * ldy + gc] = ll;
                } else {
                    Y[(size_t)(gr + r) * ldy + gc] = v;
                }
            }
        }
    }
}

// ---------------------------------------------------------------------------
// seqconv: Conv1d over L as channels (34->34, k=3, pad=1 on the di axis)
// + bias + silu; emits bf16 hi/lo pair.  One block per b, 256 threads.
// Weights staged in LDS (wave-uniform broadcast reads).
// ---------------------------------------------------------------------------
__global__ __launch_bounds__(256)
void seqconv_k(const float* __restrict__ XP, int ldxp,
               const float* __restrict__ w, const float* __restrict__ bias,
               u16* __restrict__ XCh, u16* __restrict__ XCl)
{
    const int b   = blockIdx.x;
    const int tid = threadIdx.x;
    const int tx  = tid & 63;
    const int ty  = tid >> 6;
    const int j0  = tx * 4;

    __shared__ float sx[LL][264];
    __shared__ float sw[LL][112];

    for (int idx = tid; idx < LL * 256; idx += 256) {
        int li = idx >> 8, jj = idx & 255;
        sx[li][jj + 1] = XP[(size_t)(b * LL + li) * ldxp + jj];
    }
    if (tid < LL) { sx[tid][0] = 0.f; sx[tid][257] = 0.f; }
    for (int idx = tid; idx < LL * LL * 3; idx += 256) {
        int lo = idx / 102;
        int rem = idx - lo * 102;
        int li = rem / 3;
        int k  = rem - li * 3;
        sw[li][lo * 3 + k] = w[idx];
    }
    __syncthreads();

    const int base = ty * 9 - (ty == 3 ? 1 : 0);   // 0,9,18,26
    const int cnt  = (ty < 2) ? 9 : 8;

    float acc[9][4];
    #pragma unroll
    for (int i = 0; i < 9; i++)
        #pragma unroll
        for (int jj = 0; jj < 4; jj++) acc[i][jj] = 0.f;

    for (int li = 0; li < LL; li++) {
        float4 xa = *(const float4*)&sx[li][j0];
        float2 xb = *(const float2*)&sx[li][j0 + 4];
        float xv[6] = {xa.x, xa.y, xa.z, xa.w, xb.x, xb.y};
        const float* swr = &sw[li][0];
        #pragma unroll
        for (int i = 0; i < 9; i++) {
            if (i < cnt) {
                int lo3 = (base + i) * 3;
                float w0 = swr[lo3 + 0];
                float w1 = swr[lo3 + 1];
                float w2 = swr[lo3 + 2];
                #pragma unroll
                for (int jj = 0; jj < 4; jj++) {
                    acc[i][jj] = fmaf(w0, xv[jj],     acc[i][jj]);
                    acc[i][jj] = fmaf(w1, xv[jj + 1], acc[i][jj]);
                    acc[i][jj] = fmaf(w2, xv[jj + 2], acc[i][jj]);
                }
            }
        }
    }

    #pragma unroll
    for (int i = 0; i < 9; i++) {
        if (i < cnt) {
            int lo = base + i;
            float bb = bias[lo];
            ushort4 oh, ol;
            float v0 = silu_f(acc[i][0] + bb);
            float v1 = silu_f(acc[i][1] + bb);
            float v2 = silu_f(acc[i][2] + bb);
            float v3 = silu_f(acc[i][3] + bb);
            f2pair(v0, &oh.x, &ol.x);
            f2pair(v1, &oh.y, &ol.y);
            f2pair(v2, &oh.z, &ol.z);
            f2pair(v3, &oh.w, &ol.w);
            size_t o = (size_t)(b * LL + lo) * DI + j0;
            *(ushort4*)&XCh[o] = oh;
            *(ushort4*)&XCl[o] = ol;
        }
    }
}

// ---------------------------------------------------------------------------
// Fused S6 scan, LDS-free (round-3 shape: d=64/block, grid (4,NB)).
// 256 threads: sub = tid&15 owns n in {sub*4..+3} u {64+sub*4..+3};
// pg = tid>>4 owns d = d0+pg*4..+3.  h[4][8] in regs; walking-pointer
// prefetch.  x reconstructed from xc2 bf16 pair.  Epilogue fuses the
// silu(xs)*silu(dgate) gate and emits it as a bf16 pair for the out_w GEMM.
// UNI fast path: one exp per (l,d) when A row is constant (A=ones/sqrt(N)).
// ---------------------------------------------------------------------------
template <bool UNI>
__device__ __forceinline__ void scan_loop(
    const float* __restrict__ pD,    // delta, stride 512
    const float* __restrict__ pBC,   // B|C,  stride 512
    const u16*  __restrict__ pXh,    // xc2 hi, stride 256
    const u16*  __restrict__ pXl,    // xc2 lo, stride 256
    const float* __restrict__ pG,    // dgate, stride 512
    u16* __restrict__ pGh, u16* __restrict__ pGl,  // gate pair, stride 256
    float a[4][8], float h[4][8], int sub)
{
    float4  fD  = *(const float4*)(pD);
    ushort4 fXh = *(const ushort4*)(pXh);
    ushort4 fXl = *(const ushort4*)(pXl);
    float4 fB0 = *(const float4*)(pBC);
    float4 fB1 = *(const float4*)(pBC + 64);
    float4 fC0 = *(const float4*)(pBC + 128);
    float4 fC1 = *(const float4*)(pBC + 192);

    for (int l = 0; l < LL; l++) {
        float4 cD = fD; ushort4 cXh = fXh, cXl = fXl;
        float4 cB0 = fB0, cB1 = fB1, cC0 = fC0, cC1 = fC1;
        pD += 512; pBC += 512; pXh += 256; pXl += 256;
        if (l + 1 < LL) {
            fD  = *(const float4*)(pD);
            fXh = *(const ushort4*)(pXh);
            fXl = *(const ushort4*)(pXl);
            fB0 = *(const float4*)(pBC);
            fB1 = *(const float4*)(pBC + 64);
            fC0 = *(const float4*)(pBC + 128);
            fC1 = *(const float4*)(pBC + 192);
        }

        float xv[4] = { bf2f(cXh.x) + bf2f(cXl.x), bf2f(cXh.y) + bf2f(cXl.y),
                        bf2f(cXh.z) + bf2f(cXl.z), bf2f(cXh.w) + bf2f(cXl.w) };
        float dl[4] = {cD.x, cD.y, cD.z, cD.w};
        float dx[4] = {cD.x * xv[0], cD.y * xv[1], cD.z * xv[2], cD.w * xv[3]};
        float bv[8] = {cB0.x,cB0.y,cB0.z,cB0.w,cB1.x,cB1.y,cB1.z,cB1.w};
        float cv[8] = {cC0.x,cC0.y,cC0.z,cC0.w,cC1.x,cC1.y,cC1.z,cC1.w};

        float accd[4] = {0.f, 0.f, 0.f, 0.f};
        #pragma unroll
        for (int dd = 0; dd < 4; dd++) {
            if (UNI) {
                float dA = __expf(dl[dd] * a[dd][0]);
                #pragma unroll
                for (int j = 0; j < 8; j++) {
                    h[dd][j] = fmaf(dA, h[dd][j], dx[dd] * bv[j]);
                    accd[dd] = fmaf(cv[j], h[dd][j], accd[dd]);
                }
            } else {
                #pragma unroll
                for (int j = 0; j < 8; j++) {
                    float dA = __expf(dl[dd] * a[dd][j]);
                    h[dd][j] = fmaf(dA, h[dd][j], dx[dd] * bv[j]);
                    accd[dd] = fmaf(cv[j], h[dd][j], accd[dd]);
                }
            }
        }
        #pragma unroll
        for (int dd = 0; dd < 4; dd++) {
            float v = accd[dd];
            v += __shfl_xor(v, 1);
            v += __shfl_xor(v, 2);
            v += __shfl_xor(v, 4);
            v += __shfl_xor(v, 8);
            accd[dd] = v;
        }
        if (sub == 0) {
            float4 dg = *(const float4*)(pG);
            ushort4 oh, ol;
            float g0 = silu_f(accd[0]) * silu_f(dg.x);
            float g1 = silu_f(accd[1]) * silu_f(dg.y);
            float g2 = silu_f(accd[2]) * silu_f(dg.z);
            float g3 = silu_f(accd[3]) * silu_f(dg.w);
            f2pair(g0, &oh.x, &ol.x);
            f2pair(g1, &oh.y, &ol.y);
            f2pair(g2, &oh.z, &ol.z);
            f2pair(g3, &oh.w, &ol.w);
            *(ushort4*)pGh = oh;
            *(ushort4*)pGl = ol;
        }
        pG += 512; pGh += 256; pGl += 256;
    }
}

__global__ __launch_bounds__(256)
void scan_k(const float* __restrict__ dBC,   // [8704,512] delta|Bm|Cm
            const u16*  __restrict__ Xh,     // [8704,256] xc2 hi
            const u16*  __restrict__ Xl,     // [8704,256] xc2 lo
            const float* __restrict__ A,     // [256,128]
            const float* __restrict__ DG,    // [8704,512] buf1 (dgate in cols 256+)
            u16* __restrict__ Gh, u16* __restrict__ Gl)  // [8704,256] gate pair
{
    const int b  = blockIdx.y;
    const int d0 = blockIdx.x * 64;
    const int tid = threadIdx.x;
    const int sub = tid & 15;
    const int pg  = tid >> 4;
    const int dbase = d0 + pg * 4;
    const int nA = sub * 4;

    float a[4][8], h[4][8];
    bool uni = true;
    #pragma unroll
    for (int dd = 0; dd < 4; dd++) {
        const float* Ar = A + (size_t)(dbase + dd) * NN;
        float4 q0 = *(const float4*)(Ar + nA);
        float4 q1 = *(const float4*)(Ar + 64 + nA);
        a[dd][0]=q0.x; a[dd][1]=q0.y; a[dd][2]=q0.z; a[dd][3]=q0.w;
        a[dd][4]=q1.x; a[dd][5]=q1.y; a[dd][6]=q1.z; a[dd][7]=q1.w;
        #pragma unroll
        for (int j = 0; j < 8; j++) { h[dd][j] = 0.f; uni &= (a[dd][j] == a[dd][0]); }
    }

    const float* pD  = dBC + (size_t)b * LL * 512 + dbase;
    const float* pBC = dBC + (size_t)b * LL * 512 + 256 + nA;
    const u16*  pXh = Xh  + (size_t)b * LL * 256 + dbase;
    const u16*  pXl = Xl  + (size_t)b * LL * 256 + dbase;
    const float* pG  = DG  + (size_t)b * LL * 512 + 256 + dbase;
    u16* pGh = Gh + (size_t)b * LL * 256 + dbase;
    u16* pGl = Gl + (size_t)b * LL * 256 + dbase;

    if (uni) scan_loop<true >(pD, pBC, pXh, pXl, pG, pGh, pGl, a, h, sub);
    else     scan_loop<false>(pD, pBC, pXh, pXl, pG, pGh, pGl, a, h, sub);
}

// ---------------------------------------------------------------------------
// FNN stage 1: partials[kc][b][o] = F[b, kc*256..+255] @ W1T[kc*256..+255, o]
// grid (16 btiles, 17 kchunks), 256 threads.  Deterministic split-K.
// ---------------------------------------------------------------------------
__global__ __launch_bounds__(256)
void fnn1_k(const float* __restrict__ F, const float* __restrict__ W1T,
            float* __restrict__ partials)
{
    const int btile = blockIdx.x;
    const int kc    = blockIdx.y;
    const int tid   = threadIdx.x;
    __shared__ float sf[16][260];
    for (int i = tid; i < 16 * 256; i += 256) {
        int r = i >> 8, c = i & 255;
        sf[r][c] = F[(size_t)(btile * 16 + r) * 4352 + kc * 256 + c];
    }
    __syncthreads();

    const int o  = tid & 63;
    const int bq = tid >> 6;
    const float* w = W1T + (size_t)(kc * 256) * 64 + o;
    float acc[4] = {0.f, 0.f, 0.f, 0.f};
    for (int k = 0; k < 256; k += 4) {
        float w0 = w[(size_t)(k + 0) * 64];
        float w1 = w[(size_t)(k + 1) * 64];
        float w2 = w[(size_t)(k + 2) * 64];
        float w3 = w[(size_t)(k + 3) * 64];
        #pragma unroll
        for (int bj = 0; bj < 4; bj++) {
            float4 f4 = *(const float4*)&sf[bq * 4 + bj][k];
            acc[bj] = fmaf(w0, f4.x, acc[bj]);
            acc[bj] = fmaf(w1, f4.y, acc[bj]);
            acc[bj] = fmaf(w2, f4.z, acc[bj]);
            acc[bj] = fmaf(w3, f4.w, acc[bj]);
        }
    }
    #pragma unroll
    for (int bj = 0; bj < 4; bj++)
        partials[(size_t)kc * 16384 + (btile * 16 + bq * 4 + bj) * 64 + o] = acc[bj];
}

// ---------------------------------------------------------------------------
// FNN stage 2: reduce 17 partials, leaky, then @fnn2_w.T + b2 -> out[b][32].
// ---------------------------------------------------------------------------
__global__ __launch_bounds__(64)
void fnn2_k(const float* __restrict__ partials,
            const float* __restrict__ B1,
            const float* __restrict__ W2, const float* __restrict__ B2,
            float* __restrict__ out)
{
    int b = blockIdx.x;
    int t = threadIdx.x;
    __shared__ float s1[64];
    float acc = B1[t];
    #pragma unroll
    for (int kc = 0; kc < 17; kc++)
        acc += partials[(size_t)kc * 16384 + b * 64 + t];
    s1[t] = leaky_f(acc);
    __syncthreads();

    if (t < 32) {
        float acc2 = B2[t];
        const float* w2 = W2 + t * 64;
        #pragma unroll
        for (int j = 0; j < 64; j++) acc2 = fmaf(s1[j], w2[j], acc2);
        out[(size_t)b * 32 + t] = acc2;
    }
}

// ---------------------------------------------------------------------------
extern "C" void kernel_launch(void* const* d_in, const int* in_sizes, int n_in,
                              void* d_out, int out_size, void* d_ws, size_t ws_size,
                              hipStream_t stream)
{
    const float* x        = (const float*)d_in[0];
    const float* conv_w   = (const float*)d_in[1];
    const float* conv_b   = (const float*)d_in[2];
    const float* norm_w   = (const float*)d_in[3];
    const float* inp_w    = (const float*)d_in[4];
    const float* inp_b    = (const float*)d_in[5];
    const float* seqconv_w= (const float*)d_in[6];
    const float* seqconv_b= (const float*)d_in[7];
    const float* convlin_w= (const float*)d_in[8];
    const float* convlin_b= (const float*)d_in[9];
    const float* fc1_w    = (const float*)d_in[10];
    const float* fc1_b    = (const float*)d_in[11];
    const float* fc2_w    = (const float*)d_in[12];
    const float* fc2_b    = (const float*)d_in[13];
    const float* fc3_w    = (const float*)d_in[14];
    const float* fc3_b    = (const float*)d_in[15];
    const float* A        = (const float*)d_in[16];
    const float* D_w      = (const float*)d_in[17];
    const float* D_b      = (const float*)d_in[18];
    const float* out_w    = (const float*)d_in[19];
    const float* out_b    = (const float*)d_in[20];
    const float* fnn1_w   = (const float*)d_in[21];
    const float* fnn1_b   = (const float*)d_in[22];
    const float* fnn2_w   = (const float*)d_in[23];
    const float* fnn2_b   = (const float*)d_in[24];

    // ---- workspace layout (bytes); total ~55.8 MB (proven ws >= 59.8 MB) ----
    char* W = (char*)d_ws;
    float* buf1  = (float*)(W + 0);           // [8704,512] fp32  xp|dgate
    float* buf3  = (float*)(W + 17825792);    // [8704,512] fp32  delta|B|C ; partials later
    // region_f: xn pair -> xc2h -> fout (lifetimes disjoint)
    u16*   xnh   = (u16*)  (W + 35651584);    // [8704,128]
    u16*   xnl   = (u16*)  (W + 37879808);
    u16*   xc2h  = (u16*)  (W + 35651584);    // [8704,256]
    float* fout  = (float*)(W + 35651584);    // [8704,128] fp32
    u16*   xc2l  = (u16*)  (W + 40108032);    // [8704,256]
    u16*   xch   = (u16*)  (W + 44564480);    // [8704,256] ; gateh later
    u16*   xcl   = (u16*)  (W + 49020928);    // [8704,256] ; gatel later
    float* w1t   = (float*)(W + 53477376);    // [4352,64]
    u16*   wc1h  = (u16*)  (W + 54591488);    // [512,128]
    u16*   wc1l  = (u16*)  (W + 54722560);
    u16*   wc3h  = (u16*)  (W + 54853632);    // [512,256]
    u16*   wc3l  = (u16*)  (W + 55115776);
    u16*   cvh   = (u16*)  (W + 55377920);    // [256,256]
    u16*   cvl   = (u16*)  (W + 55508992);
    u16*   owh   = (u16*)  (W + 55640064);    // [128,256]
    u16*   owl   = (u16*)  (W + 55705600);
    float* bias1 = (float*)(W + 55771136);    // [512]
    float* bias3 = (float*)(W + 55773184);    // [512]
    u16* gateh = xch;                         // xc pair dead after convlin GEMM
    u16* gatel = xcl;
    float* partials = buf3;                   // buf3 dead after scan

    prep_w_k<<<1152, 256, 0, stream>>>(inp_w, D_w, fc1_w, fc2_w, fc3_w,
                                       convlin_w, out_w,
                                       inp_b, D_b, fc1_b, fc2_b, fc3_b,
                                       wc1h, wc1l, wc3h, wc3l, cvh, cvl,
                                       owh, owl, bias1, bias3);
    transpose_k<<<68, 256, 0, stream>>>(fnn1_w, w1t);

    conv_norm_k<<<MM, 128, 0, stream>>>(x, conv_w, conv_b, norm_w, xnh, xnl);

    // buf1 = xn @ [inp_w;D_w].T + [inp_b|D_b]          (fp32 out)
    mgemm_k<128, 0><<<dim3(MM / 128, 8), 256, 0, stream>>>(
        xnh, xnl, wc1h, wc1l, bias1, buf1, 512, nullptr, nullptr);

    seqconv_k<<<NB, 256, 0, stream>>>(buf1, 512, seqconv_w, seqconv_b, xch, xcl);

    // xc2 = xc @ convlin_w.T + convlin_b               (bf16-pair out)
    mgemm_k<256, 2><<<dim3(MM / 128, 4), 256, 0, stream>>>(
        xch, xcl, cvh, cvl, convlin_b, nullptr, 256, xc2h, xc2l);

    // buf3 = xc2 @ [fc1;fc2;fc3].T + bias3, softplus on delta cols (fp32 out)
    mgemm_k<256, 1><<<dim3(MM / 128, 8), 256, 0, stream>>>(
        xc2h, xc2l, wc3h, wc3l, bias3, buf3, 512, nullptr, nullptr);

    // scan + fused gate epilogue -> gate bf16 pair
    scan_k<<<dim3(4, NB), 256, 0, stream>>>(buf3, xc2h, xc2l, A, buf1,
                                            gateh, gatel);

    // fout = gate @ out_w.T + out_b                    (fp32 out)
    mgemm_k<256, 0><<<dim3(MM / 128, 2), 256, 0, stream>>>(
        gateh, gatel, owh, owl, out_b, fout, 128, nullptr, nullptr);

    fnn1_k<<<dim3(16, 17), 256, 0, stream>>>(fout, w1t, partials);
    fnn2_k<<<NB, 64, 0, stream>>>(partials, fnn1_b, fnn2_w, fnn2_b,
                                  (float*)d_out);
}

// Round 6
// 228.853 us; speedup vs baseline: 1.7948x; 1.2658x over previous
//
#include <hip/hip_runtime.h>
#include <math.h>

// ---------------------------------------------------------------------------
// SpectralGroupAttention: conv1d+leaky+rmsnorm -> MFMA-GEMM(inp|D) -> seqconv
// -> MFMA-GEMM(convlin) -> MFMA-GEMM(fc1|2|3, softplus) -> SSD scan (uniform-A
// closed form; sequential fallback for general A) -> MFMA-GEMM(out_w) ->
// split-K FNN head.  GEMMs use split-bf16 (hi+lo, 3 MFMA products).
// B=256, L=34, d=128, di=256, N=128, M=8704.
// ---------------------------------------------------------------------------

#define NB    256
#define LL    34
#define DD    128
#define DI    256
#define NN    128
#define MM    (NB*LL)       // 8704

using u16 = unsigned short;
typedef __attribute__((ext_vector_type(8))) short short8;
typedef __attribute__((ext_vector_type(4))) float f32x4;

__device__ __forceinline__ float silu_f(float x)  { return x / (1.f + __expf(-x)); }
__device__ __forceinline__ float softplus_f(float x) {
    return fmaxf(x, 0.f) + __logf(1.f + __expf(-fabsf(x)));
}
__device__ __forceinline__ float leaky_f(float x) { return (x >= 0.f) ? x : 0.01f * x; }

__device__ __forceinline__ u16 f2bf(float x) {            // RNE fp32->bf16
    unsigned u = __float_as_uint(x);
    return (u16)((u + 0x7FFF + ((u >> 16) & 1)) >> 16);
}
__device__ __forceinline__ float bf2f(u16 h) {
    return __uint_as_float(((unsigned)h) << 16);
}
__device__ __forceinline__ void f2pair(float v, u16* h, u16* l) {
    u16 hh = f2bf(v);
    *h = hh;
    *l = f2bf(v - bf2f(hh));
}

// ---------------------------------------------------------------------------
// prep_w: convert all GEMM weights to bf16 hi/lo pairs + concat biases.
// ---------------------------------------------------------------------------
__global__ void prep_w_k(const float* __restrict__ inp_w, const float* __restrict__ D_w,
                         const float* __restrict__ fc1_w, const float* __restrict__ fc2_w,
                         const float* __restrict__ fc3_w, const float* __restrict__ convlin_w,
                         const float* __restrict__ out_w,
                         const float* __restrict__ inp_b, const float* __restrict__ D_b,
                         const float* __restrict__ fc1_b, const float* __restrict__ fc2_b,
                         const float* __restrict__ fc3_b,
                         u16* __restrict__ wc1h, u16* __restrict__ wc1l,
                         u16* __restrict__ wc3h, u16* __restrict__ wc3l,
                         u16* __restrict__ cvh,  u16* __restrict__ cvl,
                         u16* __restrict__ owh,  u16* __restrict__ owl,
                         float* __restrict__ bias1, float* __restrict__ bias3)
{
    int i = blockIdx.x * 256 + threadIdx.x;
    if (i < 65536) {
        float v = (i < 32768) ? inp_w[i] : D_w[i - 32768];
        f2pair(v, &wc1h[i], &wc1l[i]);
    } else if (i < 196608) {
        int j = i - 65536;
        float v = (j < 65536) ? fc1_w[j] : (j < 98304 ? fc2_w[j - 65536] : fc3_w[j - 98304]);
        f2pair(v, &wc3h[j], &wc3l[j]);
    } else if (i < 262144) {
        int j = i - 196608;
        f2pair(convlin_w[j], &cvh[j], &cvl[j]);
    } else if (i < 294912) {
        int j = i - 262144;
        f2pair(out_w[j], &owh[j], &owl[j]);
    }
    if (i < 512)  bias1[i] = (i < 256) ? inp_b[i] : D_b[i - 256];
    else if (i < 1024) {
        int j = i - 512;
        bias3[j] = (j < 256) ? fc1_b[j] : (j < 384 ? fc2_b[j - 256] : fc3_b[j - 384]);
    }
}

// ---------------------------------------------------------------------------
// check_uni_k: flag = 1 iff every row of A[256][128] is constant along n.
// Coalesced: elem idx vs its row base (idx & ~127).  One block, 256 threads.
// ---------------------------------------------------------------------------
__global__ __launch_bounds__(256)
void check_uni_k(const float* __restrict__ A, int* __restrict__ flag)
{
    const int tid = threadIdx.x;
    __shared__ int s;
    if (tid == 0) s = 1;
    __syncthreads();
    bool ok = true;
    for (int k = 0; k < 128; k++) {
        int idx = tid + k * 256;
        ok &= (A[idx] == A[idx & ~127]);
    }
    if (!ok) s = 0;
    __syncthreads();
    if (tid == 0) *flag = s;
}

// ---------------------------------------------------------------------------
// transpose fnn1_w [64][4352] -> W1T [4352][64] via coalesced LDS tiles.
// ---------------------------------------------------------------------------
__global__ __launch_bounds__(256)
void transpose_k(const float* __restrict__ W1, float* __restrict__ W1T)
{
    __shared__ float tile[64][65];
    const int bx = blockIdx.x;
    const int tid = threadIdx.x;
    for (int p = 0; p < 16; p++) {
        int idx = tid + p * 256;
        int r = idx >> 6, c = idx & 63;
        tile[r][c] = W1[(size_t)r * 4352 + bx * 64 + c];
    }
    __syncthreads();
    for (int p = 0; p < 16; p++) {
        int idx = tid + p * 256;
        int cc = idx >> 6, rr = idx & 63;
        W1T[(size_t)(bx * 64 + cc) * 64 + rr] = tile[rr][cc];
    }
}

// ---------------------------------------------------------------------------
// conv1d(1->128, k=20, stride=5) + bias + leaky, then RMSNorm over d=128.
// ---------------------------------------------------------------------------
__global__ __launch_bounds__(128)
void conv_norm_k(const float* __restrict__ x, const float* __restrict__ cw,
                 const float* __restrict__ cb, const float* __restrict__ nw,
                 u16* __restrict__ XNh, u16* __restrict__ XNl)
{
    int bl = blockIdx.x;
    int b = bl / LL, l = bl % LL;
    int c = threadIdx.x;
    const float* xr = x + (size_t)b * 189 + l * 5;
    float g = cb[c];
    #pragma unroll
    for (int k = 0; k < 20; k++) g = fmaf(xr[k], cw[c * 20 + k], g);
    g = leaky_f(g);

    float s = g * g;
    #pragma unroll
    for (int m = 32; m >= 1; m >>= 1) s += __shfl_xor(s, m);
    __shared__ float wsum[2];
    if ((threadIdx.x & 63) == 0) wsum[threadIdx.x >> 6] = s;
    __syncthreads();
    float mean = (wsum[0] + wsum[1]) * (1.f / 128.f);
    float inv = 1.f / sqrtf(mean + 1e-5f);
    float v = g * inv * nw[c];
    f2pair(v, &XNh[(size_t)bl * DD + c], &XNl[(size_t)bl * DD + c]);
}

// ---------------------------------------------------------------------------
// Split-bf16 MFMA GEMM (see round-5 comment).  EPI: 0 fp32; 1 fp32+softplus
// cols<256; 2 bf16-pair out.
// ---------------------------------------------------------------------------
template <int K, int EPI>
__global__ __launch_bounds__(256)
void mgemm_k(const u16* __restrict__ Ah, const u16* __restrict__ Al,
             const u16* __restrict__ Wh, const u16* __restrict__ Wl,
             const float* __restrict__ bias,
             float* __restrict__ Y, int ldy,
             u16* __restrict__ Yh, u16* __restrict__ Yl)
{
    const int tid  = threadIdx.x;
    const int r0   = blockIdx.x * 128;
    const int c0   = blockIdx.y * 64;
    const int wave = tid >> 6;
    const int lane = tid & 63;
    const int wm   = wave & 1;
    const int wn   = wave >> 1;
    const int l15  = lane & 15;
    const int lq   = lane >> 4;

    __shared__ u16 sAh[128][40];
    __shared__ u16 sAl[128][40];
    __shared__ u16 sBh[64][40];
    __shared__ u16 sBl[64][40];

    f32x4 acc[4][2];
    #pragma unroll
    for (int i = 0; i < 4; i++)
        #pragma unroll
        for (int j = 0; j < 2; j++) acc[i][j] = (f32x4){0.f, 0.f, 0.f, 0.f};

    const int a_row = tid >> 1;
    const int a_kb  = (tid & 1) * 16;
    const int b_row = tid >> 2;
    const int b_ko  = (tid & 3) * 8;

    for (int k0 = 0; k0 < K; k0 += 32) {
        const u16* ga = Ah + (size_t)(r0 + a_row) * K + k0 + a_kb;
        const u16* gl = Al + (size_t)(r0 + a_row) * K + k0 + a_kb;
        short8 vh0 = *(const short8*)(ga);
        short8 vh1 = *(const short8*)(ga + 8);
        short8 vl0 = *(const short8*)(gl);
        short8 vl1 = *(const short8*)(gl + 8);
        const u16* gb = Wh + (size_t)(c0 + b_row) * K + k0 + b_ko;
        const u16* gc = Wl + (size_t)(c0 + b_row) * K + k0 + b_ko;
        short8 wb = *(const short8*)(gb);
        short8 wc = *(const short8*)(gc);

        *(short8*)&sAh[a_row][a_kb]     = vh0;
        *(short8*)&sAh[a_row][a_kb + 8] = vh1;
        *(short8*)&sAl[a_row][a_kb]     = vl0;
        *(short8*)&sAl[a_row][a_kb + 8] = vl1;
        *(short8*)&sBh[b_row][b_ko] = wb;
        *(short8*)&sBl[b_row][b_ko] = wc;
        __syncthreads();

        short8 fah[4], fal[4], fbh[2], fbl[2];
        #pragma unroll
        for (int i = 0; i < 4; i++) {
            fah[i] = *(const short8*)&sAh[wm * 64 + i * 16 + l15][lq * 8];
            fal[i] = *(const short8*)&sAl[wm * 64 + i * 16 + l15][lq * 8];
        }
        #pragma unroll
        for (int j = 0; j < 2; j++) {
            fbh[j] = *(const short8*)&sBh[wn * 32 + j * 16 + l15][lq * 8];
            fbl[j] = *(const short8*)&sBl[wn * 32 + j * 16 + l15][lq * 8];
        }
        #pragma unroll
        for (int i = 0; i < 4; i++)
            #pragma unroll
            for (int j = 0; j < 2; j++) {
                acc[i][j] = __builtin_amdgcn_mfma_f32_16x16x32_bf16(fah[i], fbh[j], acc[i][j], 0, 0, 0);
                acc[i][j] = __builtin_amdgcn_mfma_f32_16x16x32_bf16(fah[i], fbl[j], acc[i][j], 0, 0, 0);
                acc[i][j] = __builtin_amdgcn_mfma_f32_16x16x32_bf16(fal[i], fbh[j], acc[i][j], 0, 0, 0);
            }
        __syncthreads();
    }

    #pragma unroll
    for (int i = 0; i < 4; i++) {
        int gr = r0 + wm * 64 + i * 16 + lq * 4;
        #pragma unroll
        for (int j = 0; j < 2; j++) {
            int gc = c0 + wn * 32 + j * 16 + l15;
            float bb = bias[gc];
            #pragma unroll
            for (int r = 0; r < 4; r++) {
                float v = acc[i][j][r] + bb;
                if (EPI == 1) { if (gc < 256) v = softplus_f(v); }
                if (EPI == 2) {
                    u16 hh, ll;
                    f2pair(v, &hh, &ll);
                    Yh[(size_t)(gr + r) * ldy + gc] = hh;
                    Yl[(size_t)(gr + r) * ldy + gc] = ll;
                } else {
                    Y[(size_t)(gr + r) * ldy + gc] = v;
                }
            }
        }
    }
}

// ---------------------------------------------------------------------------
// seqconv: Conv1d over L as channels + bias + silu; emits bf16 hi/lo pair.
// ---------------------------------------------------------------------------
__global__ __launch_bounds__(256)
void seqconv_k(const float* __restrict__ XP, int ldxp,
               const float* __restrict__ w, const float* __restrict__ bias,
               u16* __restrict__ XCh, u16* __restrict__ XCl)
{
    const int b   = blockIdx.x;
    const int tid = threadIdx.x;
    const int tx  = tid & 63;
    const int ty  = tid >> 6;
    const int j0  = tx * 4;

    __shared__ float sx[LL][264];
    __shared__ float sw[LL][112];

    for (int idx = tid; idx < LL * 256; idx += 256) {
        int li = idx >> 8, jj = idx & 255;
        sx[li][jj + 1] = XP[(size_t)(b * LL + li) * ldxp + jj];
    }
    if (tid < LL) { sx[tid][0] = 0.f; sx[tid][257] = 0.f; }
    for (int idx = tid; idx < LL * LL * 3; idx += 256) {
        int lo = idx / 102;
        int rem = idx - lo * 102;
        int li = rem / 3;
        int k  = rem - li * 3;
        sw[li][lo * 3 + k] = w[idx];
    }
    __syncthreads();

    const int base = ty * 9 - (ty == 3 ? 1 : 0);
    const int cnt  = (ty < 2) ? 9 : 8;

    float acc[9][4];
    #pragma unroll
    for (int i = 0; i < 9; i++)
        #pragma unroll
        for (int jj = 0; jj < 4; jj++) acc[i][jj] = 0.f;

    for (int li = 0; li < LL; li++) {
        float4 xa = *(const float4*)&sx[li][j0];
        float2 xb = *(const float2*)&sx[li][j0 + 4];
        float xv[6] = {xa.x, xa.y, xa.z, xa.w, xb.x, xb.y};
        const float* swr = &sw[li][0];
        #pragma unroll
        for (int i = 0; i < 9; i++) {
            if (i < cnt) {
                int lo3 = (base + i) * 3;
                float w0 = swr[lo3 + 0];
                float w1 = swr[lo3 + 1];
                float w2 = swr[lo3 + 2];
                #pragma unroll
                for (int jj = 0; jj < 4; jj++) {
                    acc[i][jj] = fmaf(w0, xv[jj],     acc[i][jj]);
                    acc[i][jj] = fmaf(w1, xv[jj + 1], acc[i][jj]);
                    acc[i][jj] = fmaf(w2, xv[jj + 2], acc[i][jj]);
                }
            }
        }
    }

    #pragma unroll
    for (int i = 0; i < 9; i++) {
        if (i < cnt) {
            int lo = base + i;
            float bb = bias[lo];
            ushort4 oh, ol;
            float v0 = silu_f(acc[i][0] + bb);
            float v1 = silu_f(acc[i][1] + bb);
            float v2 = silu_f(acc[i][2] + bb);
            float v3 = silu_f(acc[i][3] + bb);
            f2pair(v0, &oh.x, &ol.x);
            f2pair(v1, &oh.y, &ol.y);
            f2pair(v2, &oh.z, &ol.z);
            f2pair(v3, &oh.w, &ol.w);
            size_t o = (size_t)(b * LL + lo) * DI + j0;
            *(ushort4*)&XCh[o] = oh;
            *(ushort4*)&XCl[o] = ol;
        }
    }
}

// ---------------------------------------------------------------------------
// SSD scan (uniform-A closed form).  One block per b, thread = d (256 = di).
//   S[l,d] = cumsum_l delta[l,d]*a_d ;  u[t,d] = exp(-S_t)*delta*x
//   M[l,t] = <C_l, B_t>  (34x34x128 mini-GEMM in LDS)
//   xs[l,d] = exp(S_l) * sum_{t<=l} M[l,t] u[t,d]
// Gate epilogue fused: g = silu(xs)*silu(dgate) -> bf16 pair.
// Early-exits unless flag says A is row-uniform.
// ---------------------------------------------------------------------------
__global__ __launch_bounds__(256)
void ssd_scan_k(const int* __restrict__ flag,
                const float* __restrict__ dBC,   // [8704,512] delta|B|C
                const u16* __restrict__ Xh, const u16* __restrict__ Xl,
                const float* __restrict__ A,     // [256,128] row-uniform
                const float* __restrict__ DG,    // buf1, dgate at cols 256+
                u16* __restrict__ Gh, u16* __restrict__ Gl)
{
    if (*flag == 0) return;
    const int b   = blockIdx.x;
    const int tid = threadIdx.x;
    const int lane = tid & 63;

    __shared__ float sB[LL][132];
    __shared__ float sC[LL][132];
    __shared__ float sM[LL][36];

    const float* rowbase = dBC + (size_t)b * LL * 512;
    for (int idx = tid; idx < LL * 128; idx += 256) {
        int l = idx >> 7, n = idx & 127;
        sB[l][n] = rowbase[l * 512 + 256 + n];
        sC[l][n] = rowbase[l * 512 + 384 + n];
    }
    __syncthreads();

    // M[l][t] for t<=l; lane-rotated k to spread LDS banks
    for (int e = tid; e < LL * LL; e += 256) {
        int l = e / LL, t = e - l * LL;
        if (t <= l) {
            float acc = 0.f;
            #pragma unroll
            for (int kk = 0; kk < 32; kk++) {
                int k = ((lane + kk) & 31) * 4;
                float4 vb = *(const float4*)&sB[t][k];
                float4 vc = *(const float4*)&sC[l][k];
                acc += vb.x * vc.x + vb.y * vc.y + vb.z * vc.z + vb.w * vc.w;
            }
            sM[l][t] = acc;
        }
    }
    __syncthreads();

    const int d = tid;
    const float a_d = A[(size_t)d * NN];
    const float* pDel = rowbase + d;                       // stride 512
    const u16* pXh = Xh + (size_t)b * LL * 256 + d;        // stride 256
    const u16* pXl = Xl + (size_t)b * LL * 256 + d;

    float u[LL], eS[LL];
    float S = 0.f;
    #pragma unroll
    for (int l = 0; l < LL; l++) {
        float dl = pDel[l * 512];
        S = fmaf(dl, a_d, S);
        eS[l] = __expf(S);
        float xv = bf2f(pXh[l * 256]) + bf2f(pXl[l * 256]);
        u[l] = __expf(-S) * dl * xv;
    }

    const float* pG = DG + (size_t)b * LL * 512 + 256 + d; // stride 512
    u16* pGh = Gh + (size_t)b * LL * 256 + d;              // stride 256
    u16* pGl = Gl + (size_t)b * LL * 256 + d;
    #pragma unroll
    for (int l = 0; l < LL; l++) {
        float acc = 0.f;
        for (int t = 0; t <= l; t++) acc = fmaf(sM[l][t], u[t], acc);
        float xs = eS[l] * acc;
        float g = silu_f(xs) * silu_f(pG[l * 512]);
        u16 hh, ll2;
        f2pair(g, &hh, &ll2);
        pGh[l * 256] = hh;
        pGl[l * 256] = ll2;
    }
}

// ---------------------------------------------------------------------------
// Fallback sequential scan for general A (early-exits when A is uniform).
// Round-3 shape: d=64/block, grid (4,NB); gate epilogue fused.
// ---------------------------------------------------------------------------
__global__ __launch_bounds__(256)
void scan_fb_k(const int* __restrict__ flag,
               const float* __restrict__ dBC,
               const u16*  __restrict__ Xh, const u16* __restrict__ Xl,
               const float* __restrict__ A,
               const float* __restrict__ DG,
               u16* __restrict__ Gh, u16* __restrict__ Gl)
{
    if (*flag != 0) return;
    const int b  = blockIdx.y;
    const int d0 = blockIdx.x * 64;
    const int tid = threadIdx.x;
    const int sub = tid & 15;
    const int pg  = tid >> 4;
    const int dbase = d0 + pg * 4;
    const int nA = sub * 4;

    float a[4][8], h[4][8];
    #pragma unroll
    for (int dd = 0; dd < 4; dd++) {
        const float* Ar = A + (size_t)(dbase + dd) * NN;
        float4 q0 = *(const float4*)(Ar + nA);
        float4 q1 = *(const float4*)(Ar + 64 + nA);
        a[dd][0]=q0.x; a[dd][1]=q0.y; a[dd][2]=q0.z; a[dd][3]=q0.w;
        a[dd][4]=q1.x; a[dd][5]=q1.y; a[dd][6]=q1.z; a[dd][7]=q1.w;
        #pragma unroll
        for (int j = 0; j < 8; j++) h[dd][j] = 0.f;
    }

    const float* pD  = dBC + (size_t)b * LL * 512 + dbase;
    const float* pBC = dBC + (size_t)b * LL * 512 + 256 + nA;
    const u16*  pXh = Xh  + (size_t)b * LL * 256 + dbase;
    const u16*  pXl = Xl  + (size_t)b * LL * 256 + dbase;
    const float* pG  = DG  + (size_t)b * LL * 512 + 256 + dbase;
    u16* pGh = Gh + (size_t)b * LL * 256 + dbase;
    u16* pGl = Gl + (size_t)b * LL * 256 + dbase;

    for (int l = 0; l < LL; l++) {
        float4  cD  = *(const float4*)(pD);
        ushort4 cXh = *(const ushort4*)(pXh);
        ushort4 cXl = *(const ushort4*)(pXl);
        float4 cB0 = *(const float4*)(pBC);
        float4 cB1 = *(const float4*)(pBC + 64);
        float4 cC0 = *(const float4*)(pBC + 128);
        float4 cC1 = *(const float4*)(pBC + 192);
        pD += 512; pBC += 512; pXh += 256; pXl += 256;

        float xv[4] = { bf2f(cXh.x) + bf2f(cXl.x), bf2f(cXh.y) + bf2f(cXl.y),
                        bf2f(cXh.z) + bf2f(cXl.z), bf2f(cXh.w) + bf2f(cXl.w) };
        float dl[4] = {cD.x, cD.y, cD.z, cD.w};
        float dx[4] = {cD.x * xv[0], cD.y * xv[1], cD.z * xv[2], cD.w * xv[3]};
        float bv[8] = {cB0.x,cB0.y,cB0.z,cB0.w,cB1.x,cB1.y,cB1.z,cB1.w};
        float cv[8] = {cC0.x,cC0.y,cC0.z,cC0.w,cC1.x,cC1.y,cC1.z,cC1.w};

        float accd[4] = {0.f, 0.f, 0.f, 0.f};
        #pragma unroll
        for (int dd = 0; dd < 4; dd++)
            #pragma unroll
            for (int j = 0; j < 8; j++) {
                float dA = __expf(dl[dd] * a[dd][j]);
                h[dd][j] = fmaf(dA, h[dd][j], dx[dd] * bv[j]);
                accd[dd] = fmaf(cv[j], h[dd][j], accd[dd]);
            }
        #pragma unroll
        for (int dd = 0; dd < 4; dd++) {
            float v = accd[dd];
            v += __shfl_xor(v, 1);
            v += __shfl_xor(v, 2);
            v += __shfl_xor(v, 4);
            v += __shfl_xor(v, 8);
            accd[dd] = v;
        }
        if (sub == 0) {
            float4 dg = *(const float4*)(pG);
            ushort4 oh, ol;
            float g0 = silu_f(accd[0]) * silu_f(dg.x);
            float g1 = silu_f(accd[1]) * silu_f(dg.y);
            float g2 = silu_f(accd[2]) * silu_f(dg.z);
            float g3 = silu_f(accd[3]) * silu_f(dg.w);
            f2pair(g0, &oh.x, &ol.x);
            f2pair(g1, &oh.y, &ol.y);
            f2pair(g2, &oh.z, &ol.z);
            f2pair(g3, &oh.w, &ol.w);
            *(ushort4*)pGh = oh;
            *(ushort4*)pGl = ol;
        }
        pG += 512; pGh += 256; pGl += 256;
    }
}

// ---------------------------------------------------------------------------
// FNN stage 1: split-K partials (deterministic).
// ---------------------------------------------------------------------------
__global__ __launch_bounds__(256)
void fnn1_k(const float* __restrict__ F, const float* __restrict__ W1T,
            float* __restrict__ partials)
{
    const int btile = blockIdx.x;
    const int kc    = blockIdx.y;
    const int tid   = threadIdx.x;
    __shared__ float sf[16][260];
    for (int i = tid; i < 16 * 256; i += 256) {
        int r = i >> 8, c = i & 255;
        sf[r][c] = F[(size_t)(btile * 16 + r) * 4352 + kc * 256 + c];
    }
    __syncthreads();

    const int o  = tid & 63;
    const int bq = tid >> 6;
    const float* w = W1T + (size_t)(kc * 256) * 64 + o;
    float acc[4] = {0.f, 0.f, 0.f, 0.f};
    for (int k = 0; k < 256; k += 4) {
        float w0 = w[(size_t)(k + 0) * 64];
        float w1 = w[(size_t)(k + 1) * 64];
        float w2 = w[(size_t)(k + 2) * 64];
        float w3 = w[(size_t)(k + 3) * 64];
        #pragma unroll
        for (int bj = 0; bj < 4; bj++) {
            float4 f4 = *(const float4*)&sf[bq * 4 + bj][k];
            acc[bj] = fmaf(w0, f4.x, acc[bj]);
            acc[bj] = fmaf(w1, f4.y, acc[bj]);
            acc[bj] = fmaf(w2, f4.z, acc[bj]);
            acc[bj] = fmaf(w3, f4.w, acc[bj]);
        }
    }
    #pragma unroll
    for (int bj = 0; bj < 4; bj++)
        partials[(size_t)kc * 16384 + (btile * 16 + bq * 4 + bj) * 64 + o] = acc[bj];
}

// ---------------------------------------------------------------------------
// FNN stage 2: reduce partials, leaky, then @fnn2_w.T + b2 -> out[b][32].
// ---------------------------------------------------------------------------
__global__ __launch_bounds__(64)
void fnn2_k(const float* __restrict__ partials,
            const float* __restrict__ B1,
            const float* __restrict__ W2, const float* __restrict__ B2,
            float* __restrict__ out)
{
    int b = blockIdx.x;
    int t = threadIdx.x;
    __shared__ float s1[64];
    float acc = B1[t];
    #pragma unroll
    for (int kc = 0; kc < 17; kc++)
        acc += partials[(size_t)kc * 16384 + b * 64 + t];
    s1[t] = leaky_f(acc);
    __syncthreads();

    if (t < 32) {
        float acc2 = B2[t];
        const float* w2 = W2 + t * 64;
        #pragma unroll
        for (int j = 0; j < 64; j++) acc2 = fmaf(s1[j], w2[j], acc2);
        out[(size_t)b * 32 + t] = acc2;
    }
}

// ---------------------------------------------------------------------------
extern "C" void kernel_launch(void* const* d_in, const int* in_sizes, int n_in,
                              void* d_out, int out_size, void* d_ws, size_t ws_size,
                              hipStream_t stream)
{
    const float* x        = (const float*)d_in[0];
    const float* conv_w   = (const float*)d_in[1];
    const float* conv_b   = (const float*)d_in[2];
    const float* norm_w   = (const float*)d_in[3];
    const float* inp_w    = (const float*)d_in[4];
    const float* inp_b    = (const float*)d_in[5];
    const float* seqconv_w= (const float*)d_in[6];
    const float* seqconv_b= (const float*)d_in[7];
    const float* convlin_w= (const float*)d_in[8];
    const float* convlin_b= (const float*)d_in[9];
    const float* fc1_w    = (const float*)d_in[10];
    const float* fc1_b    = (const float*)d_in[11];
    const float* fc2_w    = (const float*)d_in[12];
    const float* fc2_b    = (const float*)d_in[13];
    const float* fc3_w    = (const float*)d_in[14];
    const float* fc3_b    = (const float*)d_in[15];
    const float* A        = (const float*)d_in[16];
    const float* D_w      = (const float*)d_in[17];
    const float* D_b      = (const float*)d_in[18];
    const float* out_w    = (const float*)d_in[19];
    const float* out_b    = (const float*)d_in[20];
    const float* fnn1_w   = (const float*)d_in[21];
    const float* fnn1_b   = (const float*)d_in[22];
    const float* fnn2_w   = (const float*)d_in[23];
    const float* fnn2_b   = (const float*)d_in[24];

    // ---- workspace layout (bytes) ----
    char* W = (char*)d_ws;
    float* buf1  = (float*)(W + 0);           // [8704,512] fp32  xp|dgate
    float* buf3  = (float*)(W + 17825792);    // [8704,512] fp32  delta|B|C ; partials later
    u16*   xnh   = (u16*)  (W + 35651584);    // [8704,128]
    u16*   xnl   = (u16*)  (W + 37879808);
    u16*   xc2h  = (u16*)  (W + 35651584);    // [8704,256] (xn dead)
    float* fout  = (float*)(W + 35651584);    // [8704,128] fp32 (later)
    u16*   xc2l  = (u16*)  (W + 40108032);    // [8704,256]
    u16*   xch   = (u16*)  (W + 44564480);    // [8704,256] ; gateh later
    u16*   xcl   = (u16*)  (W + 49020928);    // [8704,256] ; gatel later
    float* w1t   = (float*)(W + 53477376);    // [4352,64]
    u16*   wc1h  = (u16*)  (W + 54591488);
    u16*   wc1l  = (u16*)  (W + 54722560);
    u16*   wc3h  = (u16*)  (W + 54853632);
    u16*   wc3l  = (u16*)  (W + 55115776);
    u16*   cvh   = (u16*)  (W + 55377920);
    u16*   cvl   = (u16*)  (W + 55508992);
    u16*   owh   = (u16*)  (W + 55640064);
    u16*   owl   = (u16*)  (W + 55705600);
    float* bias1 = (float*)(W + 55771136);
    float* bias3 = (float*)(W + 55773184);
    int*   uflag = (int*)  (W + 55775232);
    u16* gateh = xch;
    u16* gatel = xcl;
    float* partials = buf3;

    prep_w_k<<<1152, 256, 0, stream>>>(inp_w, D_w, fc1_w, fc2_w, fc3_w,
                                       convlin_w, out_w,
                                       inp_b, D_b, fc1_b, fc2_b, fc3_b,
                                       wc1h, wc1l, wc3h, wc3l, cvh, cvl,
                                       owh, owl, bias1, bias3);
    check_uni_k<<<1, 256, 0, stream>>>(A, uflag);
    transpose_k<<<68, 256, 0, stream>>>(fnn1_w, w1t);

    conv_norm_k<<<MM, 128, 0, stream>>>(x, conv_w, conv_b, norm_w, xnh, xnl);

    // buf1 = xn @ [inp_w;D_w].T + [inp_b|D_b]          (fp32 out)
    mgemm_k<128, 0><<<dim3(MM / 128, 8), 256, 0, stream>>>(
        xnh, xnl, wc1h, wc1l, bias1, buf1, 512, nullptr, nullptr);

    seqconv_k<<<NB, 256, 0, stream>>>(buf1, 512, seqconv_w, seqconv_b, xch, xcl);

    // xc2 = xc @ convlin_w.T + convlin_b               (bf16-pair out)
    mgemm_k<256, 2><<<dim3(MM / 128, 4), 256, 0, stream>>>(
        xch, xcl, cvh, cvl, convlin_b, nullptr, 256, xc2h, xc2l);

    // buf3 = xc2 @ [fc1;fc2;fc3].T + bias3, softplus on delta cols (fp32 out)
    mgemm_k<256, 1><<<dim3(MM / 128, 8), 256, 0, stream>>>(
        xc2h, xc2l, wc3h, wc3l, bias3, buf3, 512, nullptr, nullptr);

    // SSD scan (uniform-A) OR sequential fallback -> gate bf16 pair
    ssd_scan_k<<<NB, 256, 0, stream>>>(uflag, buf3, xc2h, xc2l, A, buf1,
                                       gateh, gatel);
    scan_fb_k<<<dim3(4, NB), 256, 0, stream>>>(uflag, buf3, xc2h, xc2l, A,
                                               buf1, gateh, gatel);

    // fout = gate @ out_w.T + out_b                    (fp32 out)
    mgemm_k<256, 0><<<dim3(MM / 128, 2), 256, 0, stream>>>(
        gateh, gatel, owh, owl, out_b, fout, 128, nullptr, nullptr);

    fnn1_k<<<dim3(16, 17), 256, 0, stream>>>(fout, w1t, partials);
    fnn2_k<<<NB, 64, 0, stream>>>(partials, fnn1_b, fnn2_w, fnn2_b,
                                  (float*)d_out);
}

// Round 7
// 220.523 us; speedup vs baseline: 1.8626x; 1.0378x over previous
//
#include <hip/hip_runtime.h>
#include <math.h>

// ---------------------------------------------------------------------------
// SpectralGroupAttention: conv1d+leaky+rmsnorm -> MFMA-GEMM(inp|D) -> seqconv
// -> MFMA-GEMM(convlin) -> MFMA-GEMM(fc1|2|3, softplus, +bf16 B/C emit) ->
// SSD scan (uniform-A closed form, MFMA M = C.B^T; sequential fallback for
// general A) -> MFMA-GEMM(out_w) -> split-K FNN head.
// GEMMs use split-bf16 (hi+lo, 3 MFMA products).
// B=256, L=34, d=128, di=256, N=128, M=8704.
// ---------------------------------------------------------------------------

#define NB    256
#define LL    34
#define DD    128
#define DI    256
#define NN    128
#define MM    (NB*LL)       // 8704

using u16 = unsigned short;
typedef __attribute__((ext_vector_type(8))) short short8;
typedef __attribute__((ext_vector_type(4))) float f32x4;

__device__ __forceinline__ float silu_f(float x)  { return x / (1.f + __expf(-x)); }
__device__ __forceinline__ float softplus_f(float x) {
    return fmaxf(x, 0.f) + __logf(1.f + __expf(-fabsf(x)));
}
__device__ __forceinline__ float leaky_f(float x) { return (x >= 0.f) ? x : 0.01f * x; }

__device__ __forceinline__ u16 f2bf(float x) {            // RNE fp32->bf16
    unsigned u = __float_as_uint(x);
    return (u16)((u + 0x7FFF + ((u >> 16) & 1)) >> 16);
}
__device__ __forceinline__ float bf2f(u16 h) {
    return __uint_as_float(((unsigned)h) << 16);
}
__device__ __forceinline__ void f2pair(float v, u16* h, u16* l) {
    u16 hh = f2bf(v);
    *h = hh;
    *l = f2bf(v - bf2f(hh));
}

// ---------------------------------------------------------------------------
// prep_all: blocks [0,1152) = weight bf16-pair conversion + bias concat;
// blocks [1152,1220) = fnn1_w transpose; block 1220 = A-uniformity check.
// ---------------------------------------------------------------------------
__global__ __launch_bounds__(256)
void prep_all_k(const float* __restrict__ inp_w, const float* __restrict__ D_w,
                const float* __restrict__ fc1_w, const float* __restrict__ fc2_w,
                const float* __restrict__ fc3_w, const float* __restrict__ convlin_w,
                const float* __restrict__ out_w,
                const float* __restrict__ inp_b, const float* __restrict__ D_b,
                const float* __restrict__ fc1_b, const float* __restrict__ fc2_b,
                const float* __restrict__ fc3_b,
                const float* __restrict__ W1, const float* __restrict__ A,
                u16* __restrict__ wc1h, u16* __restrict__ wc1l,
                u16* __restrict__ wc3h, u16* __restrict__ wc3l,
                u16* __restrict__ cvh,  u16* __restrict__ cvl,
                u16* __restrict__ owh,  u16* __restrict__ owl,
                float* __restrict__ bias1, float* __restrict__ bias3,
                float* __restrict__ W1T, int* __restrict__ flag)
{
    const int bx  = blockIdx.x;
    const int tid = threadIdx.x;
    __shared__ float tile[64][65];   // used by transpose branch only

    if (bx < 1152) {
        int i = bx * 256 + tid;
        if (i < 65536) {
            float v = (i < 32768) ? inp_w[i] : D_w[i - 32768];
            f2pair(v, &wc1h[i], &wc1l[i]);
        } else if (i < 196608) {
            int j = i - 65536;
            float v = (j < 65536) ? fc1_w[j] : (j < 98304 ? fc2_w[j - 65536] : fc3_w[j - 98304]);
            f2pair(v, &wc3h[j], &wc3l[j]);
        } else if (i < 262144) {
            int j = i - 196608;
            f2pair(convlin_w[j], &cvh[j], &cvl[j]);
        } else if (i < 294912) {
            int j = i - 262144;
            f2pair(out_w[j], &owh[j], &owl[j]);
        }
        if (i < 512)  bias1[i] = (i < 256) ? inp_b[i] : D_b[i - 256];
        else if (i < 1024) {
            int j = i - 512;
            bias3[j] = (j < 256) ? fc1_b[j] : (j < 384 ? fc2_b[j - 256] : fc3_b[j - 384]);
        }
    } else if (bx < 1220) {
        const int bt = bx - 1152;         // col tile: bt*64 .. +63
        for (int p = 0; p < 16; p++) {
            int idx = tid + p * 256;
            int r = idx >> 6, c = idx & 63;
            tile[r][c] = W1[(size_t)r * 4352 + bt * 64 + c];
        }
        __syncthreads();
        for (int p = 0; p < 16; p++) {
            int idx = tid + p * 256;
            int cc = idx >> 6, rr = idx & 63;
            W1T[(size_t)(bt * 64 + cc) * 64 + rr] = tile[rr][cc];
        }
    } else {
        __shared__ int s;
        if (tid == 0) s = 1;
        __syncthreads();
        bool ok = true;
        for (int k = 0; k < 128; k++) {
            int idx = tid + k * 256;
            ok &= (A[idx] == A[idx & ~127]);
        }
        if (!ok) s = 0;
        __syncthreads();
        if (tid == 0) *flag = s;
    }
}

// ---------------------------------------------------------------------------
// conv1d(1->128, k=20, stride=5) + bias + leaky, then RMSNorm over d=128.
// ---------------------------------------------------------------------------
__global__ __launch_bounds__(128)
void conv_norm_k(const float* __restrict__ x, const float* __restrict__ cw,
                 const float* __restrict__ cb, const float* __restrict__ nw,
                 u16* __restrict__ XNh, u16* __restrict__ XNl)
{
    int bl = blockIdx.x;
    int b = bl / LL, l = bl % LL;
    int c = threadIdx.x;
    const float* xr = x + (size_t)b * 189 + l * 5;
    float g = cb[c];
    #pragma unroll
    for (int k = 0; k < 20; k++) g = fmaf(xr[k], cw[c * 20 + k], g);
    g = leaky_f(g);

    float s = g * g;
    #pragma unroll
    for (int m = 32; m >= 1; m >>= 1) s += __shfl_xor(s, m);
    __shared__ float wsum[2];
    if ((threadIdx.x & 63) == 0) wsum[threadIdx.x >> 6] = s;
    __syncthreads();
    float mean = (wsum[0] + wsum[1]) * (1.f / 128.f);
    float inv = 1.f / sqrtf(mean + 1e-5f);
    float v = g * inv * nw[c];
    f2pair(v, &XNh[(size_t)bl * DD + c], &XNl[(size_t)bl * DD + c]);
}

// ---------------------------------------------------------------------------
// Split-bf16 MFMA GEMM.  Block 128x64, 4 waves, wave tile 64x32 of 16x16,
// K-step 32; 3 MFMA per fragment pair (AhWh + AhWl + AlWh).
// EPI: 0 fp32 out; 1 fp32+softplus cols<256; 2 bf16-pair out;
//      3 fp32 out + softplus cols<256 + bf16-pair B/C emit into BC strided
//        rows (row r base = BC + r*1024: [Bh 128|Bl 128|Ch 128|Cl 128] u16).
// ---------------------------------------------------------------------------
template <int K, int EPI>
__global__ __launch_bounds__(256)
void mgemm_k(const u16* __restrict__ Ah, const u16* __restrict__ Al,
             const u16* __restrict__ Wh, const u16* __restrict__ Wl,
             const float* __restrict__ bias,
             float* __restrict__ Y, int ldy,
             u16* __restrict__ Yh, u16* __restrict__ Yl,
             u16* __restrict__ BC)
{
    const int tid  = threadIdx.x;
    const int r0   = blockIdx.x * 128;
    const int c0   = blockIdx.y * 64;
    const int wave = tid >> 6;
    const int lane = tid & 63;
    const int wm   = wave & 1;
    const int wn   = wave >> 1;
    const int l15  = lane & 15;
    const int lq   = lane >> 4;

    __shared__ u16 sAh[128][40];
    __shared__ u16 sAl[128][40];
    __shared__ u16 sBh[64][40];
    __shared__ u16 sBl[64][40];

    f32x4 acc[4][2];
    #pragma unroll
    for (int i = 0; i < 4; i++)
        #pragma unroll
        for (int j = 0; j < 2; j++) acc[i][j] = (f32x4){0.f, 0.f, 0.f, 0.f};

    const int a_row = tid >> 1;
    const int a_kb  = (tid & 1) * 16;
    const int b_row = tid >> 2;
    const int b_ko  = (tid & 3) * 8;

    for (int k0 = 0; k0 < K; k0 += 32) {
        const u16* ga = Ah + (size_t)(r0 + a_row) * K + k0 + a_kb;
        const u16* gl = Al + (size_t)(r0 + a_row) * K + k0 + a_kb;
        short8 vh0 = *(const short8*)(ga);
        short8 vh1 = *(const short8*)(ga + 8);
        short8 vl0 = *(const short8*)(gl);
        short8 vl1 = *(const short8*)(gl + 8);
        const u16* gb = Wh + (size_t)(c0 + b_row) * K + k0 + b_ko;
        const u16* gc = Wl + (size_t)(c0 + b_row) * K + k0 + b_ko;
        short8 wb = *(const short8*)(gb);
        short8 wc = *(const short8*)(gc);

        *(short8*)&sAh[a_row][a_kb]     = vh0;
        *(short8*)&sAh[a_row][a_kb + 8] = vh1;
        *(short8*)&sAl[a_row][a_kb]     = vl0;
        *(short8*)&sAl[a_row][a_kb + 8] = vl1;
        *(short8*)&sBh[b_row][b_ko] = wb;
        *(short8*)&sBl[b_row][b_ko] = wc;
        __syncthreads();

        short8 fah[4], fal[4], fbh[2], fbl[2];
        #pragma unroll
        for (int i = 0; i < 4; i++) {
            fah[i] = *(const short8*)&sAh[wm * 64 + i * 16 + l15][lq * 8];
            fal[i] = *(const short8*)&sAl[wm * 64 + i * 16 + l15][lq * 8];
        }
        #pragma unroll
        for (int j = 0; j < 2; j++) {
            fbh[j] = *(const short8*)&sBh[wn * 32 + j * 16 + l15][lq * 8];
            fbl[j] = *(const short8*)&sBl[wn * 32 + j * 16 + l15][lq * 8];
        }
        #pragma unroll
        for (int i = 0; i < 4; i++)
            #pragma unroll
            for (int j = 0; j < 2; j++) {
                acc[i][j] = __builtin_amdgcn_mfma_f32_16x16x32_bf16(fah[i], fbh[j], acc[i][j], 0, 0, 0);
                acc[i][j] = __builtin_amdgcn_mfma_f32_16x16x32_bf16(fah[i], fbl[j], acc[i][j], 0, 0, 0);
                acc[i][j] = __builtin_amdgcn_mfma_f32_16x16x32_bf16(fal[i], fbh[j], acc[i][j], 0, 0, 0);
            }
        __syncthreads();
    }

    #pragma unroll
    for (int i = 0; i < 4; i++) {
        int gr = r0 + wm * 64 + i * 16 + lq * 4;
        #pragma unroll
        for (int j = 0; j < 2; j++) {
            int gc = c0 + wn * 32 + j * 16 + l15;
            float bb = bias[gc];
            #pragma unroll
            for (int r = 0; r < 4; r++) {
                float v = acc[i][j][r] + bb;
                if (EPI == 1 || EPI == 3) { if (gc < 256) v = softplus_f(v); }
                if (EPI == 2) {
                    u16 hh, ll;
                    f2pair(v, &hh, &ll);
                    Yh[(size_t)(gr + r) * ldy + gc] = hh;
                    Yl[(size_t)(gr + r) * ldy + gc] = ll;
                } else {
                    Y[(size_t)(gr + r) * ldy + gc] = v;
                    if (EPI == 3 && gc >= 256) {
                        u16 hh, ll;
                        f2pair(v, &hh, &ll);
                        u16* rb = BC + (size_t)(gr + r) * 1024
                                     + ((gc < 384) ? 0 : 256) + (gc & 127);
                        rb[0]   = hh;
                        rb[128] = ll;
                    }
                }
            }
        }
    }
}

// ---------------------------------------------------------------------------
// seqconv: Conv1d over L as channels + bias + silu; emits bf16 hi/lo pair.
// ---------------------------------------------------------------------------
__global__ __launch_bounds__(256)
void seqconv_k(const float* __restrict__ XP, int ldxp,
               const float* __restrict__ w, const float* __restrict__ bias,
               u16* __restrict__ XCh, u16* __restrict__ XCl)
{
    const int b   = blockIdx.x;
    const int tid = threadIdx.x;
    const int tx  = tid & 63;
    const int ty  = tid >> 6;
    const int j0  = tx * 4;

    __shared__ float sx[LL][264];
    __shared__ float sw[LL][112];

    for (int idx = tid; idx < LL * 256; idx += 256) {
        int li = idx >> 8, jj = idx & 255;
        sx[li][jj + 1] = XP[(size_t)(b * LL + li) * ldxp + jj];
    }
    if (tid < LL) { sx[tid][0] = 0.f; sx[tid][257] = 0.f; }
    for (int idx = tid; idx < LL * LL * 3; idx += 256) {
        int lo = idx / 102;
        int rem = idx - lo * 102;
        int li = rem / 3;
        int k  = rem - li * 3;
        sw[li][lo * 3 + k] = w[idx];
    }
    __syncthreads();

    const int base = ty * 9 - (ty == 3 ? 1 : 0);
    const int cnt  = (ty < 2) ? 9 : 8;

    float acc[9][4];
    #pragma unroll
    for (int i = 0; i < 9; i++)
        #pragma unroll
        for (int jj = 0; jj < 4; jj++) acc[i][jj] = 0.f;

    for (int li = 0; li < LL; li++) {
        float4 xa = *(const float4*)&sx[li][j0];
        float2 xb = *(const float2*)&sx[li][j0 + 4];
        float xv[6] = {xa.x, xa.y, xa.z, xa.w, xb.x, xb.y};
        const float* swr = &sw[li][0];
        #pragma unroll
        for (int i = 0; i < 9; i++) {
            if (i < cnt) {
                int lo3 = (base + i) * 3;
                float w0 = swr[lo3 + 0];
                float w1 = swr[lo3 + 1];
                float w2 = swr[lo3 + 2];
                #pragma unroll
                for (int jj = 0; jj < 4; jj++) {
                    acc[i][jj] = fmaf(w0, xv[jj],     acc[i][jj]);
                    acc[i][jj] = fmaf(w1, xv[jj + 1], acc[i][jj]);
                    acc[i][jj] = fmaf(w2, xv[jj + 2], acc[i][jj]);
                }
            }
        }
    }

    #pragma unroll
    for (int i = 0; i < 9; i++) {
        if (i < cnt) {
            int lo = base + i;
            float bb = bias[lo];
            ushort4 oh, ol;
            float v0 = silu_f(acc[i][0] + bb);
            float v1 = silu_f(acc[i][1] + bb);
            float v2 = silu_f(acc[i][2] + bb);
            float v3 = silu_f(acc[i][3] + bb);
            f2pair(v0, &oh.x, &ol.x);
            f2pair(v1, &oh.y, &ol.y);
            f2pair(v2, &oh.z, &ol.z);
            f2pair(v3, &oh.w, &ol.w);
            size_t o = (size_t)(b * LL + lo) * DI + j0;
            *(ushort4*)&XCh[o] = oh;
            *(ushort4*)&XCl[o] = ol;
        }
    }
}

// ---------------------------------------------------------------------------
// SSD scan (uniform-A closed form).  One block per b, 256 threads.
//   M[l,t] = <C_l, B_t>   via MFMA on bf16 hi/lo pairs (3-term split):
//     3x3 tiles of 16x16 (rows padded 34->48), K = 128 in 4 steps of 32.
//   S[l,d] = cumsum delta*a_d;  u = exp(-S)*delta*x;
//   xs[l,d] = exp(S_l) * sum_{t<=l} M[l,t] u[t,d];  gate fused -> bf16 pair.
// Early-exits unless flag says A is row-uniform.
// ---------------------------------------------------------------------------
__global__ __launch_bounds__(256)
void ssd_scan_k(const int* __restrict__ flag,
                const float* __restrict__ dBC,   // [8704,512] delta|B|C fp32
                const u16* __restrict__ BC,      // strided bf16 pairs, row*1024
                const u16* __restrict__ Xh, const u16* __restrict__ Xl,
                const float* __restrict__ A,
                const float* __restrict__ DG,    // buf1, dgate at cols 256+
                u16* __restrict__ Gh, u16* __restrict__ Gl)
{
    if (*flag == 0) return;
    const int b    = blockIdx.x;
    const int tid  = threadIdx.x;
    const int wave = tid >> 6;
    const int lane = tid & 63;
    const int l15  = lane & 15;
    const int lq   = lane >> 4;

    __shared__ u16 sBh[48][136], sBl[48][136];   // row pad 136: 17 quads (odd)
    __shared__ u16 sCh[48][136], sCl[48][136];
    __shared__ float sM[48][49];

    // ---- stage bf16 B/C pairs (rows 34..47 left as don't-care) ----
    const u16* base = BC + (size_t)b * LL * 1024;
    for (int idx = tid; idx < LL * 16; idx += 256) {
        int l = idx >> 4, c = (idx & 15) << 3;
        const u16* row = base + l * 1024;
        *(short8*)&sBh[l][c] = *(const short8*)&row[c];
        *(short8*)&sBl[l][c] = *(const short8*)&row[128 + c];
        *(short8*)&sCh[l][c] = *(const short8*)&row[256 + c];
        *(short8*)&sCl[l][c] = *(const short8*)&row[384 + c];
    }
    __syncthreads();

    // ---- M = C.B^T via MFMA: tile (ti,tj), D[l=ti*16+..][t=tj*16+..] ----
    for (int tt = wave; tt < 9; tt += 4) {
        int ti = tt / 3, tj = tt - ti * 3;
        f32x4 acc = (f32x4){0.f, 0.f, 0.f, 0.f};
        #pragma unroll
        for (int ks = 0; ks < 4; ks++) {
            short8 ch = *(const short8*)&sCh[ti * 16 + l15][ks * 32 + lq * 8];
            short8 cl = *(const short8*)&sCl[ti * 16 + l15][ks * 32 + lq * 8];
            short8 bh = *(const short8*)&sBh[tj * 16 + l15][ks * 32 + lq * 8];
            short8 bl = *(const short8*)&sBl[tj * 16 + l15][ks * 32 + lq * 8];
            acc = __builtin_amdgcn_mfma_f32_16x16x32_bf16(ch, bh, acc, 0, 0, 0);
            acc = __builtin_amdgcn_mfma_f32_16x16x32_bf16(ch, bl, acc, 0, 0, 0);
            acc = __builtin_amdgcn_mfma_f32_16x16x32_bf16(cl, bh, acc, 0, 0, 0);
        }
        #pragma unroll
        for (int r = 0; r < 4; r++)
            sM[ti * 16 + lq * 4 + r][tj * 16 + l15] = acc[r];
    }
    __syncthreads();

    // ---- per-d: cumsum, u, triangular contraction, gate ----
    const int d = tid;
    const float a_d = A[(size_t)d * NN];
    const float* pDel = dBC + (size_t)b * LL * 512 + d;    // stride 512
    const u16* pXh = Xh + (size_t)b * LL * 256 + d;        // stride 256
    const u16* pXl = Xl + (size_t)b * LL * 256 + d;

    float u[LL], eS[LL];
    float S = 0.f;
    #pragma unroll
    for (int l = 0; l < LL; l++) {
        float dl = pDel[l * 512];
        S = fmaf(dl, a_d, S);
        eS[l] = __expf(S);
        float xv = bf2f(pXh[l * 256]) + bf2f(pXl[l * 256]);
        u[l] = __expf(-S) * dl * xv;
    }

    const float* pG = DG + (size_t)b * LL * 512 + 256 + d; // stride 512
    u16* pGh = Gh + (size_t)b * LL * 256 + d;              // stride 256
    u16* pGl = Gl + (size_t)b * LL * 256 + d;
    #pragma unroll
    for (int l = 0; l < LL; l++) {
        float acc = 0.f;
        for (int t = 0; t <= l; t++) acc = fmaf(sM[l][t], u[t], acc);
        float xs = eS[l] * acc;
        float g = silu_f(xs) * silu_f(pG[l * 512]);
        u16 hh, ll2;
        f2pair(g, &hh, &ll2);
        pGh[l * 256] = hh;
        pGl[l * 256] = ll2;
    }
}

// ---------------------------------------------------------------------------
// Fallback sequential scan for general A (early-exits when A is uniform).
// ---------------------------------------------------------------------------
__global__ __launch_bounds__(256)
void scan_fb_k(const int* __restrict__ flag,
               const float* __restrict__ dBC,
               const u16*  __restrict__ Xh, const u16* __restrict__ Xl,
               const float* __restrict__ A,
               const float* __restrict__ DG,
               u16* __restrict__ Gh, u16* __restrict__ Gl)
{
    if (*flag != 0) return;
    const int b  = blockIdx.y;
    const int d0 = blockIdx.x * 64;
    const int tid = threadIdx.x;
    const int sub = tid & 15;
    const int pg  = tid >> 4;
    const int dbase = d0 + pg * 4;
    const int nA = sub * 4;

    float a[4][8], h[4][8];
    #pragma unroll
    for (int dd = 0; dd < 4; dd++) {
        const float* Ar = A + (size_t)(dbase + dd) * NN;
        float4 q0 = *(const float4*)(Ar + nA);
        float4 q1 = *(const float4*)(Ar + 64 + nA);
        a[dd][0]=q0.x; a[dd][1]=q0.y; a[dd][2]=q0.z; a[dd][3]=q0.w;
        a[dd][4]=q1.x; a[dd][5]=q1.y; a[dd][6]=q1.z; a[dd][7]=q1.w;
        #pragma unroll
        for (int j = 0; j < 8; j++) h[dd][j] = 0.f;
    }

    const float* pD  = dBC + (size_t)b * LL * 512 + dbase;
    const float* pBC = dBC + (size_t)b * LL * 512 + 256 + nA;
    const u16*  pXh = Xh  + (size_t)b * LL * 256 + dbase;
    const u16*  pXl = Xl  + (size_t)b * LL * 256 + dbase;
    const float* pG  = DG  + (size_t)b * LL * 512 + 256 + dbase;
    u16* pGh = Gh + (size_t)b * LL * 256 + dbase;
    u16* pGl = Gl + (size_t)b * LL * 256 + dbase;

    for (int l = 0; l < LL; l++) {
        float4  cD  = *(const float4*)(pD);
        ushort4 cXh = *(const ushort4*)(pXh);
        ushort4 cXl = *(const ushort4*)(pXl);
        float4 cB0 = *(const float4*)(pBC);
        float4 cB1 = *(const float4*)(pBC + 64);
        float4 cC0 = *(const float4*)(pBC + 128);
        float4 cC1 = *(const float4*)(pBC + 192);
        pD += 512; pBC += 512; pXh += 256; pXl += 256;

        float xv[4] = { bf2f(cXh.x) + bf2f(cXl.x), bf2f(cXh.y) + bf2f(cXl.y),
                        bf2f(cXh.z) + bf2f(cXl.z), bf2f(cXh.w) + bf2f(cXl.w) };
        float dl[4] = {cD.x, cD.y, cD.z, cD.w};
        float dx[4] = {cD.x * xv[0], cD.y * xv[1], cD.z * xv[2], cD.w * xv[3]};
        float bv[8] = {cB0.x,cB0.y,cB0.z,cB0.w,cB1.x,cB1.y,cB1.z,cB1.w};
        float cv[8] = {cC0.x,cC0.y,cC0.z,cC0.w,cC1.x,cC1.y,cC1.z,cC1.w};

        float accd[4] = {0.f, 0.f, 0.f, 0.f};
        #pragma unroll
        for (int dd = 0; dd < 4; dd++)
            #pragma unroll
            for (int j = 0; j < 8; j++) {
                float dA = __expf(dl[dd] * a[dd][j]);
                h[dd][j] = fmaf(dA, h[dd][j], dx[dd] * bv[j]);
                accd[dd] = fmaf(cv[j], h[dd][j], accd[dd]);
            }
        #pragma unroll
        for (int dd = 0; dd < 4; dd++) {
            float v = accd[dd];
            v += __shfl_xor(v, 1);
            v += __shfl_xor(v, 2);
            v += __shfl_xor(v, 4);
            v += __shfl_xor(v, 8);
            accd[dd] = v;
        }
        if (sub == 0) {
            float4 dg = *(const float4*)(pG);
            ushort4 oh, ol;
            float g0 = silu_f(accd[0]) * silu_f(dg.x);
            float g1 = silu_f(accd[1]) * silu_f(dg.y);
            float g2 = silu_f(accd[2]) * silu_f(dg.z);
            float g3 = silu_f(accd[3]) * silu_f(dg.w);
            f2pair(g0, &oh.x, &ol.x);
            f2pair(g1, &oh.y, &ol.y);
            f2pair(g2, &oh.z, &ol.z);
            f2pair(g3, &oh.w, &ol.w);
            *(ushort4*)pGh = oh;
            *(ushort4*)pGl = ol;
        }
        pG += 512; pGh += 256; pGl += 256;
    }
}

// ---------------------------------------------------------------------------
// FNN stage 1: split-K partials (deterministic).
// ---------------------------------------------------------------------------
__global__ __launch_bounds__(256)
void fnn1_k(const float* __restrict__ F, const float* __restrict__ W1T,
            float* __restrict__ partials)
{
    const int btile = blockIdx.x;
    const int kc    = blockIdx.y;
    const int tid   = threadIdx.x;
    __shared__ float sf[16][260];
    for (int i = tid; i < 16 * 256; i += 256) {
        int r = i >> 8, c = i & 255;
        sf[r][c] = F[(size_t)(btile * 16 + r) * 4352 + kc * 256 + c];
    }
    __syncthreads();

    const int o  = tid & 63;
    const int bq = tid >> 6;
    const float* w = W1T + (size_t)(kc * 256) * 64 + o;
    float acc[4] = {0.f, 0.f, 0.f, 0.f};
    for (int k = 0; k < 256; k += 4) {
        float w0 = w[(size_t)(k + 0) * 64];
        float w1 = w[(size_t)(k + 1) * 64];
        float w2 = w[(size_t)(k + 2) * 64];
        float w3 = w[(size_t)(k + 3) * 64];
        #pragma unroll
        for (int bj = 0; bj < 4; bj++) {
            float4 f4 = *(const float4*)&sf[bq * 4 + bj][k];
            acc[bj] = fmaf(w0, f4.x, acc[bj]);
            acc[bj] = fmaf(w1, f4.y, acc[bj]);
            acc[bj] = fmaf(w2, f4.z, acc[bj]);
            acc[bj] = fmaf(w3, f4.w, acc[bj]);
        }
    }
    #pragma unroll
    for (int bj = 0; bj < 4; bj++)
        partials[(size_t)kc * 16384 + (btile * 16 + bq * 4 + bj) * 64 + o] = acc[bj];
}

// ---------------------------------------------------------------------------
// FNN stage 2: reduce partials, leaky, then @fnn2_w.T + b2 -> out[b][32].
// ---------------------------------------------------------------------------
__global__ __launch_bounds__(64)
void fnn2_k(const float* __restrict__ partials,
            const float* __restrict__ B1,
            const float* __restrict__ W2, const float* __restrict__ B2,
            float* __restrict__ out)
{
    int b = blockIdx.x;
    int t = threadIdx.x;
    __shared__ float s1[64];
    float acc = B1[t];
    #pragma unroll
    for (int kc = 0; kc < 17; kc++)
        acc += partials[(size_t)kc * 16384 + b * 64 + t];
    s1[t] = leaky_f(acc);
    __syncthreads();

    if (t < 32) {
        float acc2 = B2[t];
        const float* w2 = W2 + t * 64;
        #pragma unroll
        for (int j = 0; j < 64; j++) acc2 = fmaf(s1[j], w2[j], acc2);
        out[(size_t)b * 32 + t] = acc2;
    }
}

// ---------------------------------------------------------------------------
extern "C" void kernel_launch(void* const* d_in, const int* in_sizes, int n_in,
                              void* d_out, int out_size, void* d_ws, size_t ws_size,
                              hipStream_t stream)
{
    const float* x        = (const float*)d_in[0];
    const float* conv_w   = (const float*)d_in[1];
    const float* conv_b   = (const float*)d_in[2];
    const float* norm_w   = (const float*)d_in[3];
    const float* inp_w    = (const float*)d_in[4];
    const float* inp_b    = (const float*)d_in[5];
    const float* seqconv_w= (const float*)d_in[6];
    const float* seqconv_b= (const float*)d_in[7];
    const float* convlin_w= (const float*)d_in[8];
    const float* convlin_b= (const float*)d_in[9];
    const float* fc1_w    = (const float*)d_in[10];
    const float* fc1_b    = (const float*)d_in[11];
    const float* fc2_w    = (const float*)d_in[12];
    const float* fc2_b    = (const float*)d_in[13];
    const float* fc3_w    = (const float*)d_in[14];
    const float* fc3_b    = (const float*)d_in[15];
    const float* A        = (const float*)d_in[16];
    const float* D_w      = (const float*)d_in[17];
    const float* D_b      = (const float*)d_in[18];
    const float* out_w    = (const float*)d_in[19];
    const float* out_b    = (const float*)d_in[20];
    const float* fnn1_w   = (const float*)d_in[21];
    const float* fnn1_b   = (const float*)d_in[22];
    const float* fnn2_w   = (const float*)d_in[23];
    const float* fnn2_b   = (const float*)d_in[24];

    // ---- workspace layout (bytes) ----
    char* W = (char*)d_ws;
    float* buf1  = (float*)(W + 0);           // [8704,512] fp32  xp|dgate;
                                              // xp half reused for bf16 B/C pairs
    float* buf3  = (float*)(W + 17825792);    // [8704,512] fp32  delta|B|C ; partials later
    u16*   xnh   = (u16*)  (W + 35651584);    // [8704,128]
    u16*   xnl   = (u16*)  (W + 37879808);
    u16*   xc2h  = (u16*)  (W + 35651584);    // [8704,256] (xn dead)
    float* fout  = (float*)(W + 35651584);    // [8704,128] fp32 (later)
    u16*   xc2l  = (u16*)  (W + 40108032);    // [8704,256]
    u16*   xch   = (u16*)  (W + 44564480);    // [8704,256] ; gateh later
    u16*   xcl   = (u16*)  (W + 49020928);    // [8704,256] ; gatel later
    float* w1t   = (float*)(W + 53477376);    // [4352,64]
    u16*   wc1h  = (u16*)  (W + 54591488);
    u16*   wc1l  = (u16*)  (W + 54722560);
    u16*   wc3h  = (u16*)  (W + 54853632);
    u16*   wc3l  = (u16*)  (W + 55115776);
    u16*   cvh   = (u16*)  (W + 55377920);
    u16*   cvl   = (u16*)  (W + 55508992);
    u16*   owh   = (u16*)  (W + 55640064);
    u16*   owl   = (u16*)  (W + 55705600);
    float* bias1 = (float*)(W + 55771136);
    float* bias3 = (float*)(W + 55773184);
    int*   uflag = (int*)  (W + 55775232);
    u16* gateh = xch;
    u16* gatel = xcl;
    u16* bcpair = (u16*)buf1;                 // xp half of buf1 (dead after seqconv)
    float* partials = buf3;

    prep_all_k<<<1221, 256, 0, stream>>>(inp_w, D_w, fc1_w, fc2_w, fc3_w,
                                         convlin_w, out_w,
                                         inp_b, D_b, fc1_b, fc2_b, fc3_b,
                                         fnn1_w, A,
                                         wc1h, wc1l, wc3h, wc3l, cvh, cvl,
                                         owh, owl, bias1, bias3, w1t, uflag);

    conv_norm_k<<<MM, 128, 0, stream>>>(x, conv_w, conv_b, norm_w, xnh, xnl);

    // buf1 = xn @ [inp_w;D_w].T + [inp_b|D_b]          (fp32 out)
    mgemm_k<128, 0><<<dim3(MM / 128, 8), 256, 0, stream>>>(
        xnh, xnl, wc1h, wc1l, bias1, buf1, 512, nullptr, nullptr, nullptr);

    seqconv_k<<<NB, 256, 0, stream>>>(buf1, 512, seqconv_w, seqconv_b, xch, xcl);

    // xc2 = xc @ convlin_w.T + convlin_b               (bf16-pair out)
    mgemm_k<256, 2><<<dim3(MM / 128, 4), 256, 0, stream>>>(
        xch, xcl, cvh, cvl, convlin_b, nullptr, 256, xc2h, xc2l, nullptr);

    // buf3 = xc2 @ [fc1;fc2;fc3].T + bias3, softplus on delta cols,
    // B/C also emitted as bf16 pairs into buf1's xp half
    mgemm_k<256, 3><<<dim3(MM / 128, 8), 256, 0, stream>>>(
        xc2h, xc2l, wc3h, wc3l, bias3, buf3, 512, nullptr, nullptr, bcpair);

    // SSD scan (uniform-A, MFMA M) OR sequential fallback -> gate bf16 pair
    ssd_scan_k<<<NB, 256, 0, stream>>>(uflag, buf3, bcpair, xc2h, xc2l, A,
                                       buf1, gateh, gatel);
    scan_fb_k<<<dim3(4, NB), 256, 0, stream>>>(uflag, buf3, xc2h, xc2l, A,
                                               buf1, gateh, gatel);

    // fout = gate @ out_w.T + out_b                    (fp32 out)
    mgemm_k<256, 0><<<dim3(MM / 128, 2), 256, 0, stream>>>(
        gateh, gatel, owh, owl, out_b, fout, 128, nullptr, nullptr, nullptr);

    fnn1_k<<<dim3(16, 17), 256, 0, stream>>>(fout, w1t, partials);
    fnn2_k<<<NB, 64, 0, stream>>>(partials, fnn1_b, fnn2_w, fnn2_b,
                                  (float*)d_out);
}